// Round 10
// baseline (941.730 us; speedup 1.0000x reference)
//
#include <hip/hip_runtime.h>
#include <math.h>

#define VEN_  30000
#define Dd    620
#define Hh    1000
#define Gg    4000   // 4*H
#define Mm    1000
#define Bb    32
#define Ss    20
#define Tt    20
#define NST   470    // 2 * ceil(30000/128) stat slots per row

typedef __attribute__((ext_vector_type(8))) short short8b;  // 8 bf16
typedef __attribute__((ext_vector_type(4))) float f32x4;

typedef __attribute__((address_space(1))) void GASV;
typedef __attribute__((address_space(3))) void LASV;
#define GLOAD_LDS16(g, l) \
    __builtin_amdgcn_global_load_lds((GASV*)(const void*)(g), (LASV*)(void*)(l), 16, 0, 0)

__device__ __forceinline__ float sigf(float x) { return 1.0f / (1.0f + __expf(-x)); }
__device__ __forceinline__ ushort f2bf(float f) {            // RNE fp32->bf16
    unsigned u = __float_as_uint(f);
    u = (u + 0x7fffu + ((u >> 16) & 1u)) >> 16;
    return (ushort)u;
}
__device__ __forceinline__ float bf2f(ushort u) { return __uint_as_float(((unsigned)u) << 16); }
__device__ __forceinline__ short8b cvt8(float4 a, float4 b) {
    ushort v[8];
    v[0] = f2bf(a.x); v[1] = f2bf(a.y); v[2] = f2bf(a.z); v[3] = f2bf(a.w);
    v[4] = f2bf(b.x); v[5] = f2bf(b.y); v[6] = f2bf(b.z); v[7] = f2bf(b.w);
    return *(short8b*)v;
}

// ---------------- merged multi-tensor convert (one dispatch) ---------------
struct ConvJob { const float* src; ushort* dst; int K; int ostride; int kp8; unsigned end; };
struct ConvJobs { ConvJob j[9]; };

__global__ void conv_multi(ConvJobs jobs, unsigned total) {
    unsigned v = blockIdx.x * 256 + threadIdx.x;
    if (v >= total) return;
    int ji = 0;
    while (v >= jobs.j[ji].end) ++ji;         // 9 jobs max, ends ascending
    unsigned base = ji ? jobs.j[ji - 1].end : 0;
    unsigned local = v - base;
    const ConvJob J = jobs.j[ji];
    int rr = local / J.kp8, c8 = (local % J.kp8) * 8;
    const float* src = J.src + (size_t)rr * J.K + c8;
    short8b o;
    if (c8 + 7 < J.K) {
        o = cvt8(*(const float4*)src, *(const float4*)(src + 4));
    } else {
        ushort w[8];
        #pragma unroll
        for (int j = 0; j < 8; ++j) w[j] = (c8 + j < J.K) ? f2bf(src[j]) : (ushort)0;
        o = *(short8b*)w;
    }
    *(short8b*)&J.dst[(size_t)rr * J.ostride + c8] = o;
}

// ---------------- both embedding gathers in one dispatch -------------------
__global__ void gather2(const float* __restrict__ embA, const int* __restrict__ tokA,
                        int strA, ushort* __restrict__ outA, int osA,
                        const float* __restrict__ embB, const int* __restrict__ tokB,
                        int strB, ushort* __restrict__ outB, int osB) {
    int idx = blockIdx.x * 256 + threadIdx.x;   // 640 * 80 chunks of 8
    if (idx >= Bb * Tt * 80) return;
    const float* emb; const int* toks; int tstride; ushort* out; int ostride;
    if (blockIdx.y == 0) { emb = embA; toks = tokA; tstride = strA; out = outA; ostride = osA; }
    else                 { emb = embB; toks = tokB; tstride = strB; out = outB; ostride = osB; }
    int row = idx / 80, c8 = (idx % 80) * 8;
    int b = row / Tt, t = row % Tt;
    int tok = toks[b * tstride + t];
    const float* src = emb + (size_t)tok * Dd + c8;
    short8b o;
    if (c8 + 7 < Dd) {
        o = cvt8(*(const float4*)src, *(const float4*)(src + 4));
    } else {
        ushort v[8];
        #pragma unroll
        for (int j = 0; j < 8; ++j) v[j] = (c8 + j < Dd) ? f2bf(src[j]) : (ushort)0;
        o = *(short8b*)v;
    }
    *(short8b*)&out[(size_t)row * ostride + c8] = o;
}

// ---------------- MFMA GEMM (m97 structure + 2-phase dbuf) -----------------
// C[M,N] = A_bf16[M,Kp] * B_bf16[N,Kp]^T. 128x128 tile, 4 waves, BK=64,
// global_load_lds 16B direct staging, XOR slot swizzle both-sides (rule #21),
// double-buffered LDS: stage(next) || MFMA(cur), one barrier per K-step.
// Grid: 1D bijective XCD swizzle (m204), col-panel-major.
// MODE 0: C = acc + bias. MODE 1: logsumexp partials. MODE 2: fused maxout
// with 3-way bias sum (U_b+V_b+C_b read directly).
struct GemmArgs {
    const ushort* A; int lda;
    const ushort* B; int ldb;
    const float* bias; const float* bias2; const float* bias3;
    float* C; int ldc;
    float* pm; float* ps; ushort* Cb;
    int M, N, Kp, MT;
};

template <int MODE>
__device__ __forceinline__ void gemm_body(ushort* As, ushort* Bs, const GemmArgs g) {
    const int tid = threadIdx.x;
    const int w = tid >> 6, lane = tid & 63;
    const int wm = w >> 1, wn = w & 1;
    const int lhi = lane >> 4, llo = lane & 15;

    int nblk = gridDim.x;
    int q = nblk >> 3, r = nblk & 7;
    int xcd = blockIdx.x & 7, lo = blockIdx.x >> 3;
    int wg = ((xcd < r) ? xcd * (q + 1) : r * (q + 1) + (xcd - r) * q) + lo;
    int mt = wg % g.MT, nt = wg / g.MT;
    const int row0 = mt * 128, col0 = nt * 128;

    // staging: lane i covers LDS bytes [i*16, i*16+16) of its wave's 1KB chunk
    // = row (i>>3), slot (i&7); slot s holds logical col-slot s^(row&7).
    const int lr8 = lane >> 3;
    const int cs = (lane & 7) ^ lr8;
    const ushort* pA[4];
    const ushort* pB[4];
    #pragma unroll
    for (int qq = 0; qq < 4; ++qq) {
        int seg = w + qq * 4;
        int ra = row0 + seg * 8 + lr8; if (ra > g.M - 1) ra = g.M - 1;
        int rb = col0 + seg * 8 + lr8; if (rb > g.N - 1) rb = g.N - 1;
        pA[qq] = g.A + (size_t)ra * g.lda + cs * 8;
        pB[qq] = g.B + (size_t)rb * g.ldb + cs * 8;
    }

    f32x4 acc[4][4] = {};

    // prologue: stage k-tile 0 into buffer 0
    #pragma unroll
    for (int qq = 0; qq < 4; ++qq) {
        int seg = w + qq * 4;
        GLOAD_LDS16(pA[qq], (char*)As + (seg << 10));
        GLOAD_LDS16(pB[qq], (char*)Bs + (seg << 10));
    }
    __syncthreads();

    int cur = 0;
    for (int kk = 0; kk < g.Kp; kk += 64) {
        if (kk + 64 < g.Kp) {
            int nb = (cur ^ 1) << 14;   // byte offset of next buffer (16KB)
            #pragma unroll
            for (int qq = 0; qq < 4; ++qq) {
                int seg = w + qq * 4;
                GLOAD_LDS16(pA[qq] + kk + 64, (char*)As + nb + (seg << 10));
                GLOAD_LDS16(pB[qq] + kk + 64, (char*)Bs + nb + (seg << 10));
            }
        }
        const char* curA = (const char*)As + (cur << 14);
        const char* curB = (const char*)Bs + (cur << 14);
        #pragma unroll
        for (int ks = 0; ks < 2; ++ks) {
            short8b af[4], bg[4];
            #pragma unroll
            for (int i = 0; i < 4; ++i) {
                int Ra = wm * 64 + i * 16 + llo;
                int ca = (ks * 4 + lhi) ^ (Ra & 7);
                af[i] = *(const short8b*)(curA + Ra * 128 + (ca << 4));
                int Rb = wn * 64 + i * 16 + llo;
                int cbs = (ks * 4 + lhi) ^ (Rb & 7);
                bg[i] = *(const short8b*)(curB + Rb * 128 + (cbs << 4));
            }
            #pragma unroll
            for (int i = 0; i < 4; ++i)
                #pragma unroll
                for (int j = 0; j < 4; ++j)
                    acc[i][j] = __builtin_amdgcn_mfma_f32_16x16x32_bf16(af[i], bg[j], acc[i][j], 0, 0, 0);
        }
        __syncthreads();    // drains vmcnt(0): next buffer staged; cur reads done
        cur ^= 1;
    }

    if (MODE == 0) {
        #pragma unroll
        for (int i = 0; i < 4; ++i) {
            #pragma unroll
            for (int reg = 0; reg < 4; ++reg) {
                int row = row0 + wm * 64 + i * 16 + lhi * 4 + reg;
                if (row >= g.M) continue;
                #pragma unroll
                for (int j = 0; j < 4; ++j) {
                    int col = col0 + wn * 64 + j * 16 + llo;
                    if (col < g.N)
                        g.C[(size_t)row * g.ldc + col] = acc[i][j][reg] + (g.bias ? g.bias[col] : 0.f);
                }
            }
        }
    } else if (MODE == 1) {
        #pragma unroll
        for (int i = 0; i < 4; ++i) {
            #pragma unroll
            for (int reg = 0; reg < 4; ++reg) {
                int row = row0 + wm * 64 + i * 16 + lhi * 4 + reg;
                float vals[4], vmax = -1e30f;
                #pragma unroll
                for (int j = 0; j < 4; ++j) {
                    int col = col0 + wn * 64 + j * 16 + llo;
                    vals[j] = (col < g.N) ? (acc[i][j][reg] + g.bias[col]) : -1e30f;
                    vmax = fmaxf(vmax, vals[j]);
                }
                #pragma unroll
                for (int off = 8; off; off >>= 1) vmax = fmaxf(vmax, __shfl_xor(vmax, off, 16));
                float se = 0.f;
                #pragma unroll
                for (int j = 0; j < 4; ++j) {
                    int col = col0 + wn * 64 + j * 16 + llo;
                    if (col < g.N) se += __expf(vals[j] - vmax);
                }
                #pragma unroll
                for (int off = 8; off; off >>= 1) se += __shfl_xor(se, off, 16);
                if (llo == 0 && row < g.M) {
                    g.pm[(size_t)row * NST + nt * 2 + wn] = vmax;
                    g.ps[(size_t)row * NST + nt * 2 + wn] = se;
                }
            }
        }
    } else {   // MODE 2: fused maxout; C = tmax fp32 (ldc), Cb = bf16 [*,1024]
        #pragma unroll
        for (int i = 0; i < 4; ++i) {
            #pragma unroll
            for (int reg = 0; reg < 4; ++reg) {
                int row = row0 + wm * 64 + i * 16 + lhi * 4 + reg;
                #pragma unroll
                for (int j = 0; j < 4; ++j) {
                    int col = col0 + wn * 64 + j * 16 + llo;
                    int cc = col < g.N ? col : 0;
                    float bv = g.bias[cc] + (g.bias2 ? g.bias2[cc] : 0.f) + (g.bias3 ? g.bias3[cc] : 0.f);
                    float v = acc[i][j][reg] + bv;
                    float o = fmaxf(v, __shfl_xor(v, 1));   // pair (2m, 2m+1)
                    if (((llo & 1) == 0) && row < g.M && col + 1 < g.N) {
                        int m = col >> 1;
                        g.C[(size_t)row * g.ldc + m] = o;
                        g.Cb[(size_t)row * 1024 + m] = f2bf(o);
                    }
                }
            }
        }
    }
}

template <int MODE>
__global__ __launch_bounds__(256) void gemm_one(GemmArgs g) {
    __shared__ __align__(16) ushort As[2 * 128 * 64];
    __shared__ __align__(16) ushort Bs[2 * 128 * 64];
    gemm_body<MODE>(As, Bs, g);
}

__global__ __launch_bounds__(256) void gemm_pair(GemmArgs g0, GemmArgs g1) {
    __shared__ __align__(16) ushort As[2 * 128 * 64];
    __shared__ __align__(16) ushort Bs[2 * 128 * 64];
    if (blockIdx.y == 0) gemm_body<0>(As, Bs, g0);
    else                 gemm_body<0>(As, Bs, g1);
}

// ---------------- persistent LSTM + overlapped W_w convert ------------------
// 1D grid of 504 blocks; role = blockIdx.x & 7:
//   role 0 -> encoder col-chunk (blockIdx.x>>3), role 4 -> decoder col-chunk.
//   All chunks of one network share lid%8 -> same XCD under the round-robin
//   dispatch heuristic (locality is a PERF hint only; correctness never
//   depends on placement). Other 6 roles: convert W_w fp32->bf16, then exit.
// h traffic and flags use AGENT-scope atomics: device-coherent by contract,
// L2-local-fast when colocated. Weights hoisted to registers; xq prefetched
// at iteration top (hides HBM latency under the MFMA stage).
union HQ { unsigned long long q[2]; short8b v; };

__global__ __launch_bounds__(512) void lstm_all(
    const float* __restrict__ xpE, const float* __restrict__ xpD,
    const ushort* __restrict__ WE, const ushort* __restrict__ WD,
    ushort* __restrict__ hE, ushort* __restrict__ hD,
    int strideE, int strideD, unsigned* __restrict__ flags,
    const float* __restrict__ Ww, ushort* __restrict__ Wwb)
{
    const int role = blockIdx.x & 7;
    const int chunk = blockIdx.x >> 3;        // 0..62
    if (role != 0 && role != 4) {
        // W_w fp32->bf16 convert: 30000 rows, K=1000 -> Kp=1024 (kp8=128)
        int wid = chunk * 6 + (role < 4 ? role - 1 : role - 2);   // 0..377
        const int total = 30000 * 128;
        for (int idx = wid * 512 + (int)threadIdx.x; idx < total; idx += 378 * 512) {
            int rr = idx >> 7, c8 = (idx & 127) * 8;
            const float* src = Ww + (size_t)rr * 1000 + c8;
            short8b o;
            if (c8 + 7 < 1000) {
                o = cvt8(*(const float4*)src, *(const float4*)(src + 4));
            } else {
                ushort v[8];
                #pragma unroll
                for (int j = 0; j < 8; ++j) v[j] = (c8 + j < 1000) ? f2bf(src[j]) : (ushort)0;
                o = *(short8b*)v;
            }
            *(short8b*)&Wwb[(size_t)rr * 1024 + c8] = o;
        }
        return;
    }

    __shared__ float gsm[8][32][16];
    const int which = role >> 2;               // 0 = enc, 1 = dec
    const float* xp = which ? xpD : xpE;
    const ushort* Whh = which ? WD : WE;
    ushort* hs = which ? hD : hE;
    const int hstride = which ? strideD : strideE;
    unsigned* fl = flags + which * 64;         // 63 flags per network

    const int tid = threadIdx.x;
    const int wave = tid >> 6, l = tid & 63;
    const int g = wave & 3, half = wave >> 2;
    const int lhi = l >> 4, llo = l & 15;
    const int j0 = chunk * 16;
    const int jc = (j0 + llo < Hh) ? (j0 + llo) : (Hh - 1);
    const int kbase = half * 512;
    const ushort* wp = Whh + (size_t)(g * Hh + jc) * 1024 + kbase + lhi * 8;

    // hoist weights into registers: 16 x short8b, static indexing
    short8b wreg[16];
    #pragma unroll
    for (int kk = 0; kk < 16; ++kk) wreg[kk] = *(const short8b*)(wp + kk * 32);

    const int ub = tid >> 4, ujj = tid & 15;   // update-stage mapping
    const int ujw = j0 + ujj;
    const float* xpr = xp + (size_t)ub * Tt * Gg;
    float creg = 0.f;

    for (int t = 0; t < Tt; ++t) {
        // xq prefetch (independent of h[t-1]; hides under the MFMA stage)
        float xq0 = 0.f, xq1 = 0.f, xq2 = 0.f, xq3 = 0.f;
        if (ujw < Hh) {
            const float* xq = xpr + (size_t)t * Gg;
            xq0 = xq[ujw]; xq1 = xq[Hh + ujw]; xq2 = xq[2 * Hh + ujw]; xq3 = xq[3 * Hh + ujw];
        }

        f32x4 acc0 = {0.f, 0.f, 0.f, 0.f};
        f32x4 acc1 = {0.f, 0.f, 0.f, 0.f};
        if (t > 0) {
            const unsigned long long* h0q = (const unsigned long long*)
                (hs + ((size_t)llo * Tt + (t - 1)) * hstride + kbase + lhi * 8);
            const unsigned long long* h1q = (const unsigned long long*)
                (hs + ((size_t)(llo + 16) * Tt + (t - 1)) * hstride + kbase + lhi * 8);
            HQ a0r[4], a1r[4];
            #pragma unroll
            for (int pp = 0; pp < 4; ++pp) {
                a0r[pp].q[0] = __hip_atomic_load(h0q + pp * 8,     __ATOMIC_RELAXED, __HIP_MEMORY_SCOPE_AGENT);
                a0r[pp].q[1] = __hip_atomic_load(h0q + pp * 8 + 1, __ATOMIC_RELAXED, __HIP_MEMORY_SCOPE_AGENT);
                a1r[pp].q[0] = __hip_atomic_load(h1q + pp * 8,     __ATOMIC_RELAXED, __HIP_MEMORY_SCOPE_AGENT);
                a1r[pp].q[1] = __hip_atomic_load(h1q + pp * 8 + 1, __ATOMIC_RELAXED, __HIP_MEMORY_SCOPE_AGENT);
            }
            #pragma unroll
            for (int kk = 0; kk < 16; ++kk) {
                short8b a0 = a0r[kk & 3].v, a1 = a1r[kk & 3].v;
                if (kk + 4 < 16) {
                    a0r[kk & 3].q[0] = __hip_atomic_load(h0q + (kk + 4) * 8,     __ATOMIC_RELAXED, __HIP_MEMORY_SCOPE_AGENT);
                    a0r[kk & 3].q[1] = __hip_atomic_load(h0q + (kk + 4) * 8 + 1, __ATOMIC_RELAXED, __HIP_MEMORY_SCOPE_AGENT);
                    a1r[kk & 3].q[0] = __hip_atomic_load(h1q + (kk + 4) * 8,     __ATOMIC_RELAXED, __HIP_MEMORY_SCOPE_AGENT);
                    a1r[kk & 3].q[1] = __hip_atomic_load(h1q + (kk + 4) * 8 + 1, __ATOMIC_RELAXED, __HIP_MEMORY_SCOPE_AGENT);
                }
                acc0 = __builtin_amdgcn_mfma_f32_16x16x32_bf16(a0, wreg[kk], acc0, 0, 0, 0);
                acc1 = __builtin_amdgcn_mfma_f32_16x16x32_bf16(a1, wreg[kk], acc1, 0, 0, 0);
            }
        }
        #pragma unroll
        for (int reg = 0; reg < 4; ++reg) {
            gsm[wave][lhi * 4 + reg][llo]      = acc0[reg];
            gsm[wave][16 + lhi * 4 + reg][llo] = acc1[reg];
        }
        __syncthreads();
        {
            float hn = 0.f;
            if (ujw < Hh) {
                float vi = gsm[0][ub][ujj] + gsm[4][ub][ujj] + xq0;
                float vf = gsm[1][ub][ujj] + gsm[5][ub][ujj] + xq1;
                float vg = gsm[2][ub][ujj] + gsm[6][ub][ujj] + xq2;
                float vo = gsm[3][ub][ujj] + gsm[7][ub][ujj] + xq3;
                creg = sigf(vf) * creg + sigf(vi) * tanhf(vg);
                hn = sigf(vo) * tanhf(creg);
            }
            // pack col pairs -> one uint, AGENT-scope store (coherent point)
            unsigned mine = f2bf(hn);
            unsigned other = (unsigned)__shfl_xor((int)mine, 1);
            if (((ujj & 1) == 0) && ujw < Hh) {
                unsigned pk = (other << 16) | (mine & 0xFFFFu);
                unsigned* dst = (unsigned*)&hs[((size_t)ub * Tt + t) * hstride + ujw];
                __hip_atomic_store(dst, pk, __ATOMIC_RELAXED, __HIP_MEMORY_SCOPE_AGENT);
            }
        }
        if (t + 1 < Tt) {
            __syncthreads();                  // h-stores drained (vmcnt 0)
            if (tid == 0)
                __hip_atomic_store(&fl[chunk], (unsigned)(t + 1),
                                   __ATOMIC_RELAXED, __HIP_MEMORY_SCOPE_AGENT);
            if (tid < 64) {                   // wave 0: parallel flag poll
                unsigned tgt = (unsigned)(t + 1);
                while (true) {
                    unsigned v = (tid < 63)
                        ? __hip_atomic_load(&fl[tid], __ATOMIC_RELAXED, __HIP_MEMORY_SCOPE_AGENT)
                        : tgt;
                    if (__all(v >= tgt)) break;
                    __builtin_amdgcn_s_sleep(1);
                }
            }
            __syncthreads();                  // also protects gsm reuse
        }
    }
}

// ---------------- attention scores: one wave per (b,s,t) --------------------
__global__ __launch_bounds__(256) void attn_scores(
    const float* __restrict__ Ua, const float* __restrict__ Wa,
    const float* __restrict__ Va_w, const float* __restrict__ Va_b,
    float* __restrict__ scores)
{
    int wave = (blockIdx.x * 256 + threadIdx.x) >> 6;
    int lane = threadIdx.x & 63;
    if (wave >= Bb * Ss * Tt) return;
    int b = wave / (Ss * Tt);
    int rem = wave % (Ss * Tt);
    int s = rem / Tt, t = rem % Tt;
    const float* ua = Ua + (size_t)(b * Ss + s) * Hh;
    const float* wa = Wa + (size_t)(b * Tt + t) * Hh;
    float acc = 0.f;
    for (int h = lane; h < Hh; h += 64)
        acc += tanhf(ua[h] + wa[h]) * Va_w[h];
    #pragma unroll
    for (int off = 32; off; off >>= 1) acc += __shfl_xor(acc, off, 64);
    if (lane == 0) scores[(size_t)(b * Ss + s) * Tt + t] = acc + Va_b[0];
}

// ---------------- softmax over s + context (bf16 in, bf16 out into A_cat) --
__global__ __launch_bounds__(256) void softmax_context(
    const float* __restrict__ scores, const ushort* __restrict__ enc_hb,
    ushort* __restrict__ ctx_out, int ostride)
{
    __shared__ float w[Ss];
    int b = blockIdx.x / Tt, t = blockIdx.x % Tt;
    if (threadIdx.x == 0) {
        float sc[Ss];
        float mx = -1e30f;
        for (int s = 0; s < Ss; ++s) {
            sc[s] = scores[(size_t)(b * Ss + s) * Tt + t];
            mx = fmaxf(mx, sc[s]);
        }
        float sum = 0.f;
        for (int s = 0; s < Ss; ++s) { float e = __expf(sc[s] - mx); w[s] = e; sum += e; }
        float inv = 1.f / sum;
        for (int s = 0; s < Ss; ++s) w[s] *= inv;
    }
    __syncthreads();
    for (int h = threadIdx.x; h < Hh; h += 256) {
        float acc = 0.f;
        #pragma unroll
        for (int s = 0; s < Ss; ++s)
            acc += w[s] * bf2f(enc_hb[((size_t)b * Ss + s) * 1024 + h]);
        ctx_out[(size_t)(b * Tt + t) * ostride + h] = f2bf(acc);
    }
}

// ---------------- per-row NLL from logsumexp partials ----------------------
__global__ __launch_bounds__(256) void nll_kernel(
    const float* __restrict__ pm, const float* __restrict__ ps,
    const float* __restrict__ tmax, const float* __restrict__ Ww,
    const float* __restrict__ Wb, const int* __restrict__ y,
    float* __restrict__ nll)
{
    __shared__ float sm[4];
    int row = blockIdx.x;
    int tid = threadIdx.x;
    float mx = -1e30f;
    for (int i = tid; i < NST; i += 256) mx = fmaxf(mx, pm[(size_t)row * NST + i]);
    #pragma unroll
    for (int off = 32; off; off >>= 1) mx = fmaxf(mx, __shfl_xor(mx, off, 64));
    if ((tid & 63) == 0) sm[tid >> 6] = mx;
    __syncthreads();
    mx = fmaxf(fmaxf(sm[0], sm[1]), fmaxf(sm[2], sm[3]));
    __syncthreads();
    float s = 0.f;
    for (int i = tid; i < NST; i += 256)
        s += ps[(size_t)row * NST + i] * __expf(pm[(size_t)row * NST + i] - mx);
    #pragma unroll
    for (int off = 32; off; off >>= 1) s += __shfl_xor(s, off, 64);
    if ((tid & 63) == 0) sm[tid >> 6] = s;
    __syncthreads();
    s = sm[0] + sm[1] + sm[2] + sm[3];
    __syncthreads();
    int b = row / Tt, t = row % Tt;
    int lab = y[b * (Tt + 1) + t + 1];
    float d = 0.f;
    for (int m = tid; m < Mm; m += 256)
        d += tmax[(size_t)row * Mm + m] * Ww[(size_t)lab * Mm + m];
    #pragma unroll
    for (int off = 32; off; off >>= 1) d += __shfl_xor(d, off, 64);
    if ((tid & 63) == 0) sm[tid >> 6] = d;
    __syncthreads();
    d = sm[0] + sm[1] + sm[2] + sm[3] + Wb[lab];
    if (tid == 0) nll[row] = (mx + logf(s)) - d;
}

__global__ void loss_kernel(const float* __restrict__ nll, float* __restrict__ out) {
    __shared__ float sm[4];
    float s = 0.f;
    for (int i = threadIdx.x; i < Bb * Tt; i += 256) s += nll[i];
    #pragma unroll
    for (int off = 32; off; off >>= 1) s += __shfl_xor(s, off, 64);
    if ((threadIdx.x & 63) == 0) sm[threadIdx.x >> 6] = s;
    __syncthreads();
    if (threadIdx.x == 0) out[0] = (sm[0] + sm[1] + sm[2] + sm[3]) / (float)Bb;
}

extern "C" void kernel_launch(void* const* d_in, const int* in_sizes, int n_in,
                              void* d_out, int out_size, void* d_ws, size_t ws_size,
                              hipStream_t stream)
{
    const int* x = (const int*)d_in[0];
    const int* y = (const int*)d_in[1];
    const float* emb_de  = (const float*)d_in[2];
    const float* emb_en  = (const float*)d_in[3];
    const float* enc_Wih = (const float*)d_in[4];
    const float* enc_Whh = (const float*)d_in[5];
    const float* enc_b   = (const float*)d_in[6];
    const float* dec_Wih = (const float*)d_in[7];
    const float* dec_Whh = (const float*)d_in[8];
    const float* dec_b   = (const float*)d_in[9];
    const float* Wa_w = (const float*)d_in[10];
    const float* Wa_b = (const float*)d_in[11];
    const float* Ua_w = (const float*)d_in[12];
    const float* Ua_b = (const float*)d_in[13];
    const float* Va_w = (const float*)d_in[14];
    const float* Va_b = (const float*)d_in[15];
    const float* U_w  = (const float*)d_in[16];
    const float* U_b  = (const float*)d_in[17];
    const float* V_w  = (const float*)d_in[18];
    const float* V_b  = (const float*)d_in[19];
    const float* C_w  = (const float*)d_in[20];
    const float* C_b  = (const float*)d_in[21];
    const float* W_w  = (const float*)d_in[22];
    const float* W_b  = (const float*)d_in[23];

    char* base = (char*)d_ws;
    size_t off = 0;
    auto alloc = [&](size_t bytes) { char* p = base + off; off += (bytes + 255) & ~(size_t)255; return p; };

    float*  xp_enc   = (float*)alloc(640ull * 4000 * 4);   // alias: tmax
    float*  xp_dec   = (float*)alloc(640ull * 4000 * 4);   // alias: tmax_b
    float*  Wa       = (float*)alloc(640ull * 1000 * 4);
    float*  Ua       = (float*)alloc(640ull * 1000 * 4);
    float*  scores   = (float*)alloc((size_t)Bb * Ss * Tt * 4);
    float*  pm       = (float*)alloc(640ull * NST * 4);
    float*  ps       = (float*)alloc(640ull * NST * 4);
    float*  nll      = (float*)alloc(640ull * 4);
    ushort* e_de_b   = (ushort*)alloc(640ull * 640 * 2);
    // zero-region: A_cat | hs_enc_b | flags (contiguous, one memset)
    ushort* A_cat    = (ushort*)alloc(640ull * 2688 * 2);  // [dec_h 1024 | e_en 640 | ctx 1024]
    ushort* hs_enc_b = (ushort*)alloc(640ull * 1024 * 2);
    unsigned* flags  = (unsigned*)alloc(512);              // flags[0..62]=enc, flags[64..126]=dec
    ushort* whh_enc_b= (ushort*)alloc(4000ull * 1024 * 2);
    ushort* whh_dec_b= (ushort*)alloc(4000ull * 1024 * 2);
    ushort* wbig     = (ushort*)alloc(30000ull * 1024 * 2); // W_w_b; wih bufs overlay (dead before W_w conv)
    ushort* Wcat_b   = (ushort*)alloc(2000ull * 2688 * 2);
    ushort* Wa_w_b   = (ushort*)alloc(1000ull * 1024 * 2);
    ushort* Ua_w_b   = (ushort*)alloc(1000ull * 1024 * 2);

    ushort* wih_enc_b = wbig;                               // 4000*640 each, dead after xp GEMMs
    ushort* wih_dec_b = wbig + 4000ull * 640;
    ushort* W_w_b     = wbig;

    float*  tmax   = xp_enc + 640ull * 2000;                // 640*1000 f32
    ushort* tmax_b = (ushort*)xp_dec;                       // 640*1024 bf16

    dim3 blk(256);

    // one memset covers A_cat pads + hs_enc_b pads + flag arrays
    hipMemsetAsync(A_cat, 0, 640ull * 2688 * 2 + 640ull * 1024 * 2 + 512, stream);

    // ---- all small weight conversions in ONE dispatch (W_w handled inside lstm_all)
    ConvJobs jobs;
    unsigned acc = 0;
    auto J = [&](int i, const float* s, ushort* d, int K, int ostr, int kp8, int R) {
        acc += (unsigned)R * kp8;
        jobs.j[i] = ConvJob{s, d, K, ostr, kp8, acc};
    };
    J(0, enc_Whh, whh_enc_b, 1000, 1024, 128, 4000);
    J(1, dec_Whh, whh_dec_b, 1000, 1024, 128, 4000);
    J(2, enc_Wih, wih_enc_b,  620,  640,  80, 4000);
    J(3, dec_Wih, wih_dec_b,  620,  640,  80, 4000);
    J(4, Wa_w,    Wa_w_b,    1000, 1024, 128, 1000);
    J(5, Ua_w,    Ua_w_b,    1000, 1024, 128, 1000);
    J(6, U_w,     Wcat_b,          1000, 2688, 128, 2000);
    J(7, V_w,     Wcat_b + 1024,    620, 2688,  80, 2000);
    J(8, C_w,     Wcat_b + 1664,   1000, 2688, 128, 2000);
    conv_multi<<<dim3((acc + 255) / 256), blk, 0, stream>>>(jobs, acc);

    // ---- both embedding gathers in one dispatch
    gather2<<<dim3(200, 2), blk, 0, stream>>>(emb_de, x, Ss, e_de_b, 640,
                                              emb_en, y, Tt + 1, A_cat + 1024, 2688);

    // ---- xp pair: e @ Wih^T + b  [640,4000], Kp=640  (enc & dec in one launch)
    GemmArgs ge = {e_de_b, 640, wih_enc_b, 640, enc_b, nullptr, nullptr,
                   xp_enc, 4000, nullptr, nullptr, nullptr, 640, 4000, 640, 5};
    GemmArgs gd = {A_cat + 1024, 2688, wih_dec_b, 640, dec_b, nullptr, nullptr,
                   xp_dec, 4000, nullptr, nullptr, nullptr, 640, 4000, 640, 5};
    gemm_pair<<<dim3(160, 2), blk, 0, stream>>>(ge, gd);

    // ---- persistent LSTM (20 steps, enc+dec) + overlapped W_w convert
    //      (wih bufs in wbig are dead: xp GEMMs completed before this launch)
    lstm_all<<<dim3(504), dim3(512), 0, stream>>>(
        xp_enc, xp_dec, whh_enc_b, whh_dec_b, hs_enc_b, A_cat, 1024, 2688, flags,
        W_w, W_w_b);

    // ---- attention projections pair  [640,1000], Kp=1024
    GemmArgs gw = {A_cat, 2688, Wa_w_b, 1024, Wa_b, nullptr, nullptr,
                   Wa, 1000, nullptr, nullptr, nullptr, 640, 1000, 1024, 5};
    GemmArgs gu = {hs_enc_b, 1024, Ua_w_b, 1024, Ua_b, nullptr, nullptr,
                   Ua, 1000, nullptr, nullptr, nullptr, 640, 1000, 1024, 5};
    gemm_pair<<<dim3(40, 2), blk, 0, stream>>>(gw, gu);

    attn_scores<<<dim3(3200), blk, 0, stream>>>(Ua, Wa, Va_w, Va_b, scores);
    softmax_context<<<dim3(640), blk, 0, stream>>>(scores, hs_enc_b, A_cat + 1664, 2688);

    // ---- tmax_b pad cols must be zero; xp_dec dead after last LSTM step
    hipMemsetAsync(tmax_b, 0, 640ull * 1024 * 2, stream);

    // ---- u-GEMM with fused maxout + 3-way bias  [640,2000], Kp=2688
    GemmArgs gm = {A_cat, 2688, Wcat_b, 2688, U_b, V_b, C_b,
                   tmax, 1000, nullptr, nullptr, tmax_b, 640, 2000, 2688, 5};
    gemm_one<2><<<dim3(80), blk, 0, stream>>>(gm);

    // ---- logits GEMM + fused logsumexp partials  [640,30000], Kp=1024
    GemmArgs gl = {tmax_b, 1024, W_w_b, 1024, W_b, nullptr, nullptr,
                   nullptr, 0, pm, ps, nullptr, 640, VEN_, 1024, 5};
    gemm_one<1><<<dim3(1175), blk, 0, stream>>>(gl);

    nll_kernel<<<dim3(640), blk, 0, stream>>>(pm, ps, tmax, W_w, W_b, y, nll);
    loss_kernel<<<dim3(1), blk, 0, stream>>>(nll, (float*)d_out);
}

// Round 11
// 531.878 us; speedup vs baseline: 1.7706x; 1.7706x over previous
//
#include <hip/hip_runtime.h>
#include <math.h>

#define VEN_  30000
#define Dd    620
#define Hh    1000
#define Gg    4000   // 4*H
#define Mm    1000
#define Bb    32
#define Ss    20
#define Tt    20
#define NST   470    // 2 * ceil(30000/128) stat slots per row

typedef __attribute__((ext_vector_type(8))) short short8b;  // 8 bf16
typedef __attribute__((ext_vector_type(4))) float f32x4;

typedef __attribute__((address_space(1))) void GASV;
typedef __attribute__((address_space(3))) void LASV;
#define GLOAD_LDS16(g, l) \
    __builtin_amdgcn_global_load_lds((GASV*)(const void*)(g), (LASV*)(void*)(l), 16, 0, 0)

__device__ __forceinline__ float sigf(float x) { return 1.0f / (1.0f + __expf(-x)); }
__device__ __forceinline__ ushort f2bf(float f) {            // RNE fp32->bf16
    unsigned u = __float_as_uint(f);
    u = (u + 0x7fffu + ((u >> 16) & 1u)) >> 16;
    return (ushort)u;
}
__device__ __forceinline__ float bf2f(ushort u) { return __uint_as_float(((unsigned)u) << 16); }
__device__ __forceinline__ short8b cvt8(float4 a, float4 b) {
    ushort v[8];
    v[0] = f2bf(a.x); v[1] = f2bf(a.y); v[2] = f2bf(a.z); v[3] = f2bf(a.w);
    v[4] = f2bf(b.x); v[5] = f2bf(b.y); v[6] = f2bf(b.z); v[7] = f2bf(b.w);
    return *(short8b*)v;
}

// ---------------- fp32 -> bf16 convert, vectorized, K-padded ---------------
__global__ void conv_bf16(const float* __restrict__ in, int K,
                          ushort* __restrict__ out, int ostride, int kp8, int total) {
    int idx = blockIdx.x * 256 + threadIdx.x;
    if (idx >= total) return;                 // total = R * kp8
    int rr = idx / kp8, c8 = (idx % kp8) * 8;
    const float* src = in + (size_t)rr * K + c8;
    short8b o;
    if (c8 + 7 < K) {
        o = cvt8(*(const float4*)src, *(const float4*)(src + 4));
    } else {
        ushort v[8];
        #pragma unroll
        for (int j = 0; j < 8; ++j) v[j] = (c8 + j < K) ? f2bf(src[j]) : (ushort)0;
        o = *(short8b*)v;
    }
    *(short8b*)&out[(size_t)rr * ostride + c8] = o;
}

// ---------------- merged multi-tensor convert (one dispatch) ---------------
struct ConvJob { const float* src; ushort* dst; int K; int ostride; int kp8; unsigned end; };
struct ConvJobs { ConvJob j[9]; };

__global__ void conv_multi(ConvJobs jobs, unsigned total) {
    unsigned v = blockIdx.x * 256 + threadIdx.x;
    if (v >= total) return;
    int ji = 0;
    while (v >= jobs.j[ji].end) ++ji;         // 9 jobs max, ends ascending
    unsigned base = ji ? jobs.j[ji - 1].end : 0;
    unsigned local = v - base;
    const ConvJob J = jobs.j[ji];
    int rr = local / J.kp8, c8 = (local % J.kp8) * 8;
    const float* src = J.src + (size_t)rr * J.K + c8;
    short8b o;
    if (c8 + 7 < J.K) {
        o = cvt8(*(const float4*)src, *(const float4*)(src + 4));
    } else {
        ushort w[8];
        #pragma unroll
        for (int j = 0; j < 8; ++j) w[j] = (c8 + j < J.K) ? f2bf(src[j]) : (ushort)0;
        o = *(short8b*)w;
    }
    *(short8b*)&J.dst[(size_t)rr * J.ostride + c8] = o;
}

// ---------------- both embedding gathers in one dispatch -------------------
__global__ void gather2(const float* __restrict__ embA, const int* __restrict__ tokA,
                        int strA, ushort* __restrict__ outA, int osA,
                        const float* __restrict__ embB, const int* __restrict__ tokB,
                        int strB, ushort* __restrict__ outB, int osB) {
    int idx = blockIdx.x * 256 + threadIdx.x;   // 640 * 80 chunks of 8
    if (idx >= Bb * Tt * 80) return;
    const float* emb; const int* toks; int tstride; ushort* out; int ostride;
    if (blockIdx.y == 0) { emb = embA; toks = tokA; tstride = strA; out = outA; ostride = osA; }
    else                 { emb = embB; toks = tokB; tstride = strB; out = outB; ostride = osB; }
    int row = idx / 80, c8 = (idx % 80) * 8;
    int b = row / Tt, t = row % Tt;
    int tok = toks[b * tstride + t];
    const float* src = emb + (size_t)tok * Dd + c8;
    short8b o;
    if (c8 + 7 < Dd) {
        o = cvt8(*(const float4*)src, *(const float4*)(src + 4));
    } else {
        ushort v[8];
        #pragma unroll
        for (int j = 0; j < 8; ++j) v[j] = (c8 + j < Dd) ? f2bf(src[j]) : (ushort)0;
        o = *(short8b*)v;
    }
    *(short8b*)&out[(size_t)row * ostride + c8] = o;
}

// ---------------- MFMA GEMM (m97 structure + 2-phase dbuf) -----------------
// C[M,N] = A_bf16[M,Kp] * B_bf16[N,Kp]^T. 128x128 tile, 4 waves, BK=64,
// global_load_lds 16B direct staging, XOR slot swizzle both-sides (rule #21),
// double-buffered LDS: stage(next) || MFMA(cur), one barrier per K-step.
// Grid: 1D bijective XCD swizzle (m204), col-panel-major.
// MODE 0: C = acc + bias. MODE 1: logsumexp partials. MODE 2: fused maxout
// with 3-way bias sum + pad-slot zeroing (replaces the tmax_b memset).
struct GemmArgs {
    const ushort* A; int lda;
    const ushort* B; int ldb;
    const float* bias; const float* bias2; const float* bias3;
    float* C; int ldc;
    float* pm; float* ps; ushort* Cb;
    int M, N, Kp, MT;
};

template <int MODE>
__device__ __forceinline__ void gemm_body(ushort* As, ushort* Bs, const GemmArgs g) {
    const int tid = threadIdx.x;
    const int w = tid >> 6, lane = tid & 63;
    const int wm = w >> 1, wn = w & 1;
    const int lhi = lane >> 4, llo = lane & 15;

    int nblk = gridDim.x;
    int q = nblk >> 3, r = nblk & 7;
    int xcd = blockIdx.x & 7, lo = blockIdx.x >> 3;
    int wg = ((xcd < r) ? xcd * (q + 1) : r * (q + 1) + (xcd - r) * q) + lo;
    int mt = wg % g.MT, nt = wg / g.MT;
    const int row0 = mt * 128, col0 = nt * 128;

    // staging: lane i covers LDS bytes [i*16, i*16+16) of its wave's 1KB chunk
    // = row (i>>3), slot (i&7); slot s holds logical col-slot s^(row&7).
    const int lr8 = lane >> 3;
    const int cs = (lane & 7) ^ lr8;
    const ushort* pA[4];
    const ushort* pB[4];
    #pragma unroll
    for (int qq = 0; qq < 4; ++qq) {
        int seg = w + qq * 4;
        int ra = row0 + seg * 8 + lr8; if (ra > g.M - 1) ra = g.M - 1;
        int rb = col0 + seg * 8 + lr8; if (rb > g.N - 1) rb = g.N - 1;
        pA[qq] = g.A + (size_t)ra * g.lda + cs * 8;
        pB[qq] = g.B + (size_t)rb * g.ldb + cs * 8;
    }

    f32x4 acc[4][4] = {};

    // prologue: stage k-tile 0 into buffer 0
    #pragma unroll
    for (int qq = 0; qq < 4; ++qq) {
        int seg = w + qq * 4;
        GLOAD_LDS16(pA[qq], (char*)As + (seg << 10));
        GLOAD_LDS16(pB[qq], (char*)Bs + (seg << 10));
    }
    __syncthreads();

    int cur = 0;
    for (int kk = 0; kk < g.Kp; kk += 64) {
        if (kk + 64 < g.Kp) {
            int nb = (cur ^ 1) << 14;   // byte offset of next buffer (16KB)
            #pragma unroll
            for (int qq = 0; qq < 4; ++qq) {
                int seg = w + qq * 4;
                GLOAD_LDS16(pA[qq] + kk + 64, (char*)As + nb + (seg << 10));
                GLOAD_LDS16(pB[qq] + kk + 64, (char*)Bs + nb + (seg << 10));
            }
        }
        const char* curA = (const char*)As + (cur << 14);
        const char* curB = (const char*)Bs + (cur << 14);
        #pragma unroll
        for (int ks = 0; ks < 2; ++ks) {
            short8b af[4], bg[4];
            #pragma unroll
            for (int i = 0; i < 4; ++i) {
                int Ra = wm * 64 + i * 16 + llo;
                int ca = (ks * 4 + lhi) ^ (Ra & 7);
                af[i] = *(const short8b*)(curA + Ra * 128 + (ca << 4));
                int Rb = wn * 64 + i * 16 + llo;
                int cbs = (ks * 4 + lhi) ^ (Rb & 7);
                bg[i] = *(const short8b*)(curB + Rb * 128 + (cbs << 4));
            }
            #pragma unroll
            for (int i = 0; i < 4; ++i)
                #pragma unroll
                for (int j = 0; j < 4; ++j)
                    acc[i][j] = __builtin_amdgcn_mfma_f32_16x16x32_bf16(af[i], bg[j], acc[i][j], 0, 0, 0);
        }
        __syncthreads();    // drains vmcnt(0): next buffer staged; cur reads done
        cur ^= 1;
    }

    if (MODE == 0) {
        #pragma unroll
        for (int i = 0; i < 4; ++i) {
            #pragma unroll
            for (int reg = 0; reg < 4; ++reg) {
                int row = row0 + wm * 64 + i * 16 + lhi * 4 + reg;
                if (row >= g.M) continue;
                #pragma unroll
                for (int j = 0; j < 4; ++j) {
                    int col = col0 + wn * 64 + j * 16 + llo;
                    if (col < g.N)
                        g.C[(size_t)row * g.ldc + col] = acc[i][j][reg] + (g.bias ? g.bias[col] : 0.f);
                }
            }
        }
    } else if (MODE == 1) {
        #pragma unroll
        for (int i = 0; i < 4; ++i) {
            #pragma unroll
            for (int reg = 0; reg < 4; ++reg) {
                int row = row0 + wm * 64 + i * 16 + lhi * 4 + reg;
                float vals[4], vmax = -1e30f;
                #pragma unroll
                for (int j = 0; j < 4; ++j) {
                    int col = col0 + wn * 64 + j * 16 + llo;
                    vals[j] = (col < g.N) ? (acc[i][j][reg] + g.bias[col]) : -1e30f;
                    vmax = fmaxf(vmax, vals[j]);
                }
                #pragma unroll
                for (int off = 8; off; off >>= 1) vmax = fmaxf(vmax, __shfl_xor(vmax, off, 16));
                float se = 0.f;
                #pragma unroll
                for (int j = 0; j < 4; ++j) {
                    int col = col0 + wn * 64 + j * 16 + llo;
                    if (col < g.N) se += __expf(vals[j] - vmax);
                }
                #pragma unroll
                for (int off = 8; off; off >>= 1) se += __shfl_xor(se, off, 16);
                if (llo == 0 && row < g.M) {
                    g.pm[(size_t)row * NST + nt * 2 + wn] = vmax;
                    g.ps[(size_t)row * NST + nt * 2 + wn] = se;
                }
            }
        }
    } else {   // MODE 2: fused maxout; C = tmax fp32 (ldc), Cb = bf16 [*,1024]
        #pragma unroll
        for (int i = 0; i < 4; ++i) {
            #pragma unroll
            for (int reg = 0; reg < 4; ++reg) {
                int row = row0 + wm * 64 + i * 16 + lhi * 4 + reg;
                #pragma unroll
                for (int j = 0; j < 4; ++j) {
                    int col = col0 + wn * 64 + j * 16 + llo;
                    int cc = col < g.N ? col : 0;
                    float bv = g.bias[cc] + (g.bias2 ? g.bias2[cc] : 0.f) + (g.bias3 ? g.bias3[cc] : 0.f);
                    float v = acc[i][j][reg] + bv;
                    float o = fmaxf(v, __shfl_xor(v, 1));   // pair (2m, 2m+1)
                    if (((llo & 1) == 0) && row < g.M) {
                        int m = col >> 1;
                        if (col + 1 < g.N) {
                            g.C[(size_t)row * g.ldc + m] = o;
                            g.Cb[(size_t)row * 1024 + m] = f2bf(o);
                        } else if (col >= g.N && m < 1024) {
                            g.Cb[(size_t)row * 1024 + m] = 0;   // pad slots 1000..1023
                        }
                    }
                }
            }
        }
    }
}

template <int MODE>
__global__ __launch_bounds__(256) void gemm_one(GemmArgs g) {
    __shared__ __align__(16) ushort As[2 * 128 * 64];
    __shared__ __align__(16) ushort Bs[2 * 128 * 64];
    gemm_body<MODE>(As, Bs, g);
}

__global__ __launch_bounds__(256) void gemm_pair(GemmArgs g0, GemmArgs g1) {
    __shared__ __align__(16) ushort As[2 * 128 * 64];
    __shared__ __align__(16) ushort Bs[2 * 128 * 64];
    if (blockIdx.y == 0) gemm_body<0>(As, Bs, g0);
    else                 gemm_body<0>(As, Bs, g1);
}

// ---------------- persistent LSTM: all 20 steps, enc+dec, one dispatch ------
// (R9-verified variant: 232 us.) grid (63,2) = 126 blocks co-resident.
// Weights hoisted to registers. h stores are SYSTEM-scope relaxed packed
// pairs (write-through -> no dirty L2 -> no wbl2 fence). Barrier = per-block
// flag array; release = one system store; poll = wave 0 reading all 63 flags
// in parallel. Readers of h[t-1] are first-touch lines (t-indexed).
__global__ __launch_bounds__(512) void lstm_all(
    const float* __restrict__ xpE, const float* __restrict__ xpD,
    const ushort* __restrict__ WE, const ushort* __restrict__ WD,
    ushort* __restrict__ hE, ushort* __restrict__ hD,
    int strideE, int strideD, unsigned* __restrict__ flags)
{
    __shared__ float gsm[8][32][16];
    const int which = blockIdx.y;
    const float* xp = which ? xpD : xpE;
    const ushort* Whh = which ? WD : WE;
    ushort* hs = which ? hD : hE;
    const int hstride = which ? strideD : strideE;
    unsigned* fl = flags + which * 64;         // 63 flags per network

    const int tid = threadIdx.x;
    const int wave = tid >> 6, l = tid & 63;
    const int g = wave & 3, half = wave >> 2;
    const int lhi = l >> 4, llo = l & 15;
    const int j0 = blockIdx.x * 16;
    const int jc = (j0 + llo < Hh) ? (j0 + llo) : (Hh - 1);
    const int kbase = half * 512;
    const ushort* wp = Whh + (size_t)(g * Hh + jc) * 1024 + kbase + lhi * 8;

    // hoist weights into registers: 16 x short8b, static indexing
    short8b wreg[16];
    #pragma unroll
    for (int kk = 0; kk < 16; ++kk) wreg[kk] = *(const short8b*)(wp + kk * 32);

    const int ub = tid >> 4, ujj = tid & 15;   // update-stage mapping
    const int ujw = j0 + ujj;
    const float* xpr = xp + (size_t)ub * Tt * Gg;
    float creg = 0.f;

    for (int t = 0; t < Tt; ++t) {
        f32x4 acc0 = {0.f, 0.f, 0.f, 0.f};
        f32x4 acc1 = {0.f, 0.f, 0.f, 0.f};
        if (t > 0) {
            const ushort* h0p = hs + ((size_t)llo * Tt + (t - 1)) * hstride + kbase + lhi * 8;
            const ushort* h1p = hs + ((size_t)(llo + 16) * Tt + (t - 1)) * hstride + kbase + lhi * 8;
            short8b a0r[4], a1r[4];
            #pragma unroll
            for (int pp = 0; pp < 4; ++pp) {
                a0r[pp] = *(const short8b*)(h0p + pp * 32);
                a1r[pp] = *(const short8b*)(h1p + pp * 32);
            }
            #pragma unroll
            for (int kk = 0; kk < 16; ++kk) {
                short8b a0 = a0r[kk & 3], a1 = a1r[kk & 3];
                if (kk + 4 < 16) {
                    a0r[kk & 3] = *(const short8b*)(h0p + (kk + 4) * 32);
                    a1r[kk & 3] = *(const short8b*)(h1p + (kk + 4) * 32);
                }
                acc0 = __builtin_amdgcn_mfma_f32_16x16x32_bf16(a0, wreg[kk], acc0, 0, 0, 0);
                acc1 = __builtin_amdgcn_mfma_f32_16x16x32_bf16(a1, wreg[kk], acc1, 0, 0, 0);
            }
        }
        #pragma unroll
        for (int reg = 0; reg < 4; ++reg) {
            gsm[wave][lhi * 4 + reg][llo]      = acc0[reg];
            gsm[wave][16 + lhi * 4 + reg][llo] = acc1[reg];
        }
        __syncthreads();
        {
            const float* xq = xpr + (size_t)t * Gg;
            float hn = 0.f;
            if (ujw < Hh) {
                float vi = gsm[0][ub][ujj] + gsm[4][ub][ujj] + xq[ujw];
                float vf = gsm[1][ub][ujj] + gsm[5][ub][ujj] + xq[Hh + ujw];
                float vg = gsm[2][ub][ujj] + gsm[6][ub][ujj] + xq[2 * Hh + ujw];
                float vo = gsm[3][ub][ujj] + gsm[7][ub][ujj] + xq[3 * Hh + ujw];
                creg = sigf(vf) * creg + sigf(vi) * tanhf(vg);
                hn = sigf(vo) * tanhf(creg);
            }
            // pack col pairs -> one uint, system-scope write-through store.
            unsigned mine = f2bf(hn);
            unsigned other = (unsigned)__shfl_xor((int)mine, 1);
            if (((ujj & 1) == 0) && ujw < Hh) {
                unsigned pk = (other << 16) | (mine & 0xFFFFu);
                unsigned* dst = (unsigned*)&hs[((size_t)ub * Tt + t) * hstride + ujw];
                __hip_atomic_store(dst, pk, __ATOMIC_RELAXED, __HIP_MEMORY_SCOPE_SYSTEM);
            }
        }
        if (t + 1 < Tt) {
            __syncthreads();                  // h-stores drained (vmcnt 0)
            if (tid == 0)
                __hip_atomic_store(&fl[blockIdx.x], (unsigned)(t + 1),
                                   __ATOMIC_RELAXED, __HIP_MEMORY_SCOPE_SYSTEM);
            if (tid < 64) {                   // wave 0: parallel flag poll
                unsigned tgt = (unsigned)(t + 1);
                while (true) {
                    unsigned v = (tid < 63)
                        ? __hip_atomic_load(&fl[tid], __ATOMIC_RELAXED, __HIP_MEMORY_SCOPE_SYSTEM)
                        : tgt;
                    if (__all(v >= tgt)) break;
                    __builtin_amdgcn_s_sleep(1);
                }
            }
            __syncthreads();                  // also protects gsm reuse
        }
    }
}

// ---------------- fused attention: scores + softmax + context ---------------
// one block per (b,t): 4 waves x 5 scores (wave-reduced tanh dots) ->
// LDS softmax over 20 -> context accumulation -> bf16 into A_cat.
__global__ __launch_bounds__(256) void attn_fused(
    const float* __restrict__ Ua, const float* __restrict__ Wa,
    const float* __restrict__ Va_w, const float* __restrict__ Va_b,
    const ushort* __restrict__ enc_hb, ushort* __restrict__ ctx_out, int ostride)
{
    __shared__ float sw[Ss];
    int b = blockIdx.x / Tt, t = blockIdx.x % Tt;
    int wave = threadIdx.x >> 6, lane = threadIdx.x & 63;
    const float* wa = Wa + (size_t)(b * Tt + t) * Hh;
    for (int s = wave; s < Ss; s += 4) {
        const float* ua = Ua + (size_t)(b * Ss + s) * Hh;
        float acc = 0.f;
        for (int h = lane; h < Hh; h += 64)
            acc += tanhf(ua[h] + wa[h]) * Va_w[h];
        #pragma unroll
        for (int off = 32; off; off >>= 1) acc += __shfl_xor(acc, off, 64);
        if (lane == 0) sw[s] = acc + Va_b[0];
    }
    __syncthreads();
    if (threadIdx.x == 0) {
        float mx = -1e30f;
        for (int s = 0; s < Ss; ++s) mx = fmaxf(mx, sw[s]);
        float sum = 0.f;
        for (int s = 0; s < Ss; ++s) { float e = __expf(sw[s] - mx); sw[s] = e; sum += e; }
        float inv = 1.f / sum;
        for (int s = 0; s < Ss; ++s) sw[s] *= inv;
    }
    __syncthreads();
    for (int h = threadIdx.x; h < Hh; h += 256) {
        float acc = 0.f;
        #pragma unroll
        for (int s = 0; s < Ss; ++s)
            acc += sw[s] * bf2f(enc_hb[((size_t)b * Ss + s) * 1024 + h]);
        ctx_out[(size_t)(b * Tt + t) * ostride + h] = f2bf(acc);
    }
}

// ---------------- per-row NLL from logsumexp partials ----------------------
__global__ __launch_bounds__(256) void nll_kernel(
    const float* __restrict__ pm, const float* __restrict__ ps,
    const float* __restrict__ tmax, const float* __restrict__ Ww,
    const float* __restrict__ Wb, const int* __restrict__ y,
    float* __restrict__ nll)
{
    __shared__ float sm[4];
    int row = blockIdx.x;
    int tid = threadIdx.x;
    float mx = -1e30f;
    for (int i = tid; i < NST; i += 256) mx = fmaxf(mx, pm[(size_t)row * NST + i]);
    #pragma unroll
    for (int off = 32; off; off >>= 1) mx = fmaxf(mx, __shfl_xor(mx, off, 64));
    if ((tid & 63) == 0) sm[tid >> 6] = mx;
    __syncthreads();
    mx = fmaxf(fmaxf(sm[0], sm[1]), fmaxf(sm[2], sm[3]));
    __syncthreads();
    float s = 0.f;
    for (int i = tid; i < NST; i += 256)
        s += ps[(size_t)row * NST + i] * __expf(pm[(size_t)row * NST + i] - mx);
    #pragma unroll
    for (int off = 32; off; off >>= 1) s += __shfl_xor(s, off, 64);
    if ((tid & 63) == 0) sm[tid >> 6] = s;
    __syncthreads();
    s = sm[0] + sm[1] + sm[2] + sm[3];
    __syncthreads();
    int b = row / Tt, t = row % Tt;
    int lab = y[b * (Tt + 1) + t + 1];
    float d = 0.f;
    for (int m = tid; m < Mm; m += 256)
        d += tmax[(size_t)row * Mm + m] * Ww[(size_t)lab * Mm + m];
    #pragma unroll
    for (int off = 32; off; off >>= 1) d += __shfl_xor(d, off, 64);
    if ((tid & 63) == 0) sm[tid >> 6] = d;
    __syncthreads();
    d = sm[0] + sm[1] + sm[2] + sm[3] + Wb[lab];
    if (tid == 0) nll[row] = (mx + logf(s)) - d;
}

__global__ void loss_kernel(const float* __restrict__ nll, float* __restrict__ out) {
    __shared__ float sm[4];
    float s = 0.f;
    for (int i = threadIdx.x; i < Bb * Tt; i += 256) s += nll[i];
    #pragma unroll
    for (int off = 32; off; off >>= 1) s += __shfl_xor(s, off, 64);
    if ((threadIdx.x & 63) == 0) sm[threadIdx.x >> 6] = s;
    __syncthreads();
    if (threadIdx.x == 0) out[0] = (sm[0] + sm[1] + sm[2] + sm[3]) / (float)Bb;
}

extern "C" void kernel_launch(void* const* d_in, const int* in_sizes, int n_in,
                              void* d_out, int out_size, void* d_ws, size_t ws_size,
                              hipStream_t stream)
{
    const int* x = (const int*)d_in[0];
    const int* y = (const int*)d_in[1];
    const float* emb_de  = (const float*)d_in[2];
    const float* emb_en  = (const float*)d_in[3];
    const float* enc_Wih = (const float*)d_in[4];
    const float* enc_Whh = (const float*)d_in[5];
    const float* enc_b   = (const float*)d_in[6];
    const float* dec_Wih = (const float*)d_in[7];
    const float* dec_Whh = (const float*)d_in[8];
    const float* dec_b   = (const float*)d_in[9];
    const float* Wa_w = (const float*)d_in[10];
    const float* Wa_b = (const float*)d_in[11];
    const float* Ua_w = (const float*)d_in[12];
    const float* Ua_b = (const float*)d_in[13];
    const float* Va_w = (const float*)d_in[14];
    const float* Va_b = (const float*)d_in[15];
    const float* U_w  = (const float*)d_in[16];
    const float* U_b  = (const float*)d_in[17];
    const float* V_w  = (const float*)d_in[18];
    const float* V_b  = (const float*)d_in[19];
    const float* C_w  = (const float*)d_in[20];
    const float* C_b  = (const float*)d_in[21];
    const float* W_w  = (const float*)d_in[22];
    const float* W_b  = (const float*)d_in[23];

    char* base = (char*)d_ws;
    size_t off = 0;
    auto alloc = [&](size_t bytes) { char* p = base + off; off += (bytes + 255) & ~(size_t)255; return p; };

    float*  xp_enc   = (float*)alloc(640ull * 4000 * 4);   // alias: tmax
    float*  xp_dec   = (float*)alloc(640ull * 4000 * 4);   // alias: tmax_b
    float*  Wa       = (float*)alloc(640ull * 1000 * 4);
    float*  Ua       = (float*)alloc(640ull * 1000 * 4);
    float*  pm       = (float*)alloc(640ull * NST * 4);
    float*  ps       = (float*)alloc(640ull * NST * 4);
    float*  nll      = (float*)alloc(640ull * 4);
    ushort* e_de_b   = (ushort*)alloc(640ull * 640 * 2);
    // zero-region: A_cat | hs_enc_b | flags (contiguous, one memset)
    ushort* A_cat    = (ushort*)alloc(640ull * 2688 * 2);  // [dec_h 1024 | e_en 640 | ctx 1024]
    ushort* hs_enc_b = (ushort*)alloc(640ull * 1024 * 2);
    unsigned* flags  = (unsigned*)alloc(512);              // flags[0..62]=enc, flags[64..126]=dec
    ushort* whh_enc_b= (ushort*)alloc(4000ull * 1024 * 2);
    ushort* whh_dec_b= (ushort*)alloc(4000ull * 1024 * 2);
    ushort* wbig     = (ushort*)alloc(30000ull * 1024 * 2); // W_w_b; wih bufs overlay (dead before W_w conv)
    ushort* Wcat_b   = (ushort*)alloc(2000ull * 2688 * 2);
    ushort* Wa_w_b   = (ushort*)alloc(1000ull * 1024 * 2);
    ushort* Ua_w_b   = (ushort*)alloc(1000ull * 1024 * 2);

    ushort* wih_enc_b = wbig;                               // 4000*640 each, dead after xp GEMMs
    ushort* wih_dec_b = wbig + 4000ull * 640;
    ushort* W_w_b     = wbig;

    float*  tmax   = xp_enc + 640ull * 2000;                // 640*1000 f32
    ushort* tmax_b = (ushort*)xp_dec;                       // 640*1024 bf16

    dim3 blk(256);

    // one memset covers A_cat pads + hs_enc_b pads + flag arrays
    hipMemsetAsync(A_cat, 0, 640ull * 2688 * 2 + 640ull * 1024 * 2 + 512, stream);

    // ---- all small weight conversions in ONE dispatch
    ConvJobs jobs;
    unsigned acc = 0;
    auto J = [&](int i, const float* s, ushort* d, int K, int ostr, int kp8, int R) {
        acc += (unsigned)R * kp8;
        jobs.j[i] = ConvJob{s, d, K, ostr, kp8, acc};
    };
    J(0, enc_Whh, whh_enc_b, 1000, 1024, 128, 4000);
    J(1, dec_Whh, whh_dec_b, 1000, 1024, 128, 4000);
    J(2, enc_Wih, wih_enc_b,  620,  640,  80, 4000);
    J(3, dec_Wih, wih_dec_b,  620,  640,  80, 4000);
    J(4, Wa_w,    Wa_w_b,    1000, 1024, 128, 1000);
    J(5, Ua_w,    Ua_w_b,    1000, 1024, 128, 1000);
    J(6, U_w,     Wcat_b,          1000, 2688, 128, 2000);
    J(7, V_w,     Wcat_b + 1024,    620, 2688,  80, 2000);
    J(8, C_w,     Wcat_b + 1664,   1000, 2688, 128, 2000);
    conv_multi<<<dim3((acc + 255) / 256), blk, 0, stream>>>(jobs, acc);

    // ---- both embedding gathers in one dispatch
    gather2<<<dim3(200, 2), blk, 0, stream>>>(emb_de, x, Ss, e_de_b, 640,
                                              emb_en, y, Tt + 1, A_cat + 1024, 2688);

    // ---- xp pair: e @ Wih^T + b  [640,4000], Kp=640  (enc & dec in one launch)
    GemmArgs ge = {e_de_b, 640, wih_enc_b, 640, enc_b, nullptr, nullptr,
                   xp_enc, 4000, nullptr, nullptr, nullptr, 640, 4000, 640, 5};
    GemmArgs gd = {A_cat + 1024, 2688, wih_dec_b, 640, dec_b, nullptr, nullptr,
                   xp_dec, 4000, nullptr, nullptr, nullptr, 640, 4000, 640, 5};
    gemm_pair<<<dim3(160, 2), blk, 0, stream>>>(ge, gd);

    // ---- W_w -> bf16 (overlays wih buffers; xp GEMMs above consumed them)
    conv_bf16<<<dim3(15000), blk, 0, stream>>>(W_w, 1000, W_w_b, 1024, 128, 30000 * 128);

    // ---- persistent LSTM: all 20 steps, enc+dec, one dispatch (R9 variant)
    lstm_all<<<dim3(63, 2), dim3(512), 0, stream>>>(
        xp_enc, xp_dec, whh_enc_b, whh_dec_b, hs_enc_b, A_cat, 1024, 2688, flags);

    // ---- attention projections pair  [640,1000], Kp=1024
    GemmArgs gw = {A_cat, 2688, Wa_w_b, 1024, Wa_b, nullptr, nullptr,
                   Wa, 1000, nullptr, nullptr, nullptr, 640, 1000, 1024, 5};
    GemmArgs gu = {hs_enc_b, 1024, Ua_w_b, 1024, Ua_b, nullptr, nullptr,
                   Ua, 1000, nullptr, nullptr, nullptr, 640, 1000, 1024, 5};
    gemm_pair<<<dim3(40, 2), blk, 0, stream>>>(gw, gu);

    // ---- fused attention: scores + softmax + context (one dispatch)
    attn_fused<<<dim3(640), blk, 0, stream>>>(Ua, Wa, Va_w, Va_b,
                                              hs_enc_b, A_cat + 1664, 2688);

    // ---- u-GEMM with fused maxout + 3-way bias + pad-zeroing  [640,2000]
    GemmArgs gm = {A_cat, 2688, Wcat_b, 2688, U_b, V_b, C_b,
                   tmax, 1000, nullptr, nullptr, tmax_b, 640, 2000, 2688, 5};
    gemm_one<2><<<dim3(80), blk, 0, stream>>>(gm);

    // ---- logits GEMM + fused logsumexp partials  [640,30000], Kp=1024
    GemmArgs gl = {tmax_b, 1024, W_w_b, 1024, W_b, nullptr, nullptr,
                   nullptr, 0, pm, ps, nullptr, 640, VEN_, 1024, 5};
    gemm_one<1><<<dim3(1175), blk, 0, stream>>>(gl);

    nll_kernel<<<dim3(640), blk, 0, stream>>>(pm, ps, tmax, W_w, W_b, y, nll);
    loss_kernel<<<dim3(1), blk, 0, stream>>>(nll, (float*)d_out);
}

// Round 12
// 519.774 us; speedup vs baseline: 1.8118x; 1.0233x over previous
//
#include <hip/hip_runtime.h>
#include <math.h>

#define VEN_  30000
#define Dd    620
#define Hh    1000
#define Gg    4000   // 4*H
#define Mm    1000
#define Bb    32
#define Ss    20
#define Tt    20
#define NST   470    // 2 * ceil(30000/128) stat slots per row

typedef __attribute__((ext_vector_type(8))) short short8b;  // 8 bf16
typedef __attribute__((ext_vector_type(4))) float f32x4;

typedef __attribute__((address_space(1))) void GASV;
typedef __attribute__((address_space(3))) void LASV;
#define GLOAD_LDS16(g, l) \
    __builtin_amdgcn_global_load_lds((GASV*)(const void*)(g), (LASV*)(void*)(l), 16, 0, 0)

__device__ __forceinline__ float sigf(float x) { return 1.0f / (1.0f + __expf(-x)); }
__device__ __forceinline__ ushort f2bf(float f) {            // RNE fp32->bf16
    unsigned u = __float_as_uint(f);
    u = (u + 0x7fffu + ((u >> 16) & 1u)) >> 16;
    return (ushort)u;
}
__device__ __forceinline__ float bf2f(ushort u) { return __uint_as_float(((unsigned)u) << 16); }
__device__ __forceinline__ short8b cvt8(float4 a, float4 b) {
    ushort v[8];
    v[0] = f2bf(a.x); v[1] = f2bf(a.y); v[2] = f2bf(a.z); v[3] = f2bf(a.w);
    v[4] = f2bf(b.x); v[5] = f2bf(b.y); v[6] = f2bf(b.z); v[7] = f2bf(b.w);
    return *(short8b*)v;
}

// ---------------- fp32 -> bf16 convert, vectorized, K-padded (fallback) ----
__global__ void conv_bf16(const float* __restrict__ in, int K,
                          ushort* __restrict__ out, int ostride, int kp8, int total) {
    int idx = blockIdx.x * 256 + threadIdx.x;
    if (idx >= total) return;                 // total = R * kp8
    int rr = idx / kp8, c8 = (idx % kp8) * 8;
    const float* src = in + (size_t)rr * K + c8;
    short8b o;
    if (c8 + 7 < K) {
        o = cvt8(*(const float4*)src, *(const float4*)(src + 4));
    } else {
        ushort v[8];
        #pragma unroll
        for (int j = 0; j < 8; ++j) v[j] = (c8 + j < K) ? f2bf(src[j]) : (ushort)0;
        o = *(short8b*)v;
    }
    *(short8b*)&out[(size_t)rr * ostride + c8] = o;
}

// ------- merged multi-tensor convert + embedding gathers (one dispatch) -----
// Job with tok==null: plain row convert (src row rr). Job with tok!=null:
// embedding gather: src row = tok[(rr/20)*tstride + rr%20], K=620.
struct ConvJob {
    const float* src; ushort* dst; const int* tok;
    unsigned end; int K; int ostride; int kp8; int tstride;
};
struct ConvJobs { ConvJob j[12]; };

__global__ void conv_multi(ConvJobs jobs, unsigned total) {
    unsigned v = blockIdx.x * 256 + threadIdx.x;
    if (v >= total) return;
    int ji = 0;
    while (v >= jobs.j[ji].end) ++ji;         // ends ascending, bounded
    unsigned base = ji ? jobs.j[ji - 1].end : 0;
    unsigned local = v - base;
    const ConvJob J = jobs.j[ji];
    int rr = local / J.kp8, c8 = (local % J.kp8) * 8;
    int srow = rr;
    if (J.tok) srow = J.tok[(rr / Tt) * J.tstride + (rr % Tt)];
    const float* src = J.src + (size_t)srow * J.K + c8;
    short8b o;
    if (c8 + 7 < J.K) {
        o = cvt8(*(const float4*)src, *(const float4*)(src + 4));
    } else {
        ushort w[8];
        #pragma unroll
        for (int j = 0; j < 8; ++j) w[j] = (c8 + j < J.K) ? f2bf(src[j]) : (ushort)0;
        o = *(short8b*)w;
    }
    *(short8b*)&J.dst[(size_t)rr * J.ostride + c8] = o;
}

// ---------------- MFMA GEMM (m97 structure + 2-phase dbuf) -----------------
// C[M,N] = A_bf16[M,Kp] * B_bf16[N,Kp]^T. 128x128 tile, 4 waves, BK=64,
// global_load_lds 16B direct staging, XOR slot swizzle both-sides (rule #21),
// double-buffered LDS: stage(next) || MFMA(cur), one barrier per K-step.
// Grid: 1D bijective XCD swizzle (m204), col-panel-major.
// MODE 0: C = acc + bias. MODE 1: logsumexp partials. MODE 2: fused maxout
// with 3-way bias sum + pad-slot zeroing (replaces the tmax_b memset).
struct GemmArgs {
    const ushort* A; int lda;
    const ushort* B; int ldb;
    const float* bias; const float* bias2; const float* bias3;
    float* C; int ldc;
    float* pm; float* ps; ushort* Cb;
    int M, N, Kp, MT;
};

template <int MODE>
__device__ __forceinline__ void gemm_body(ushort* As, ushort* Bs, const GemmArgs g) {
    const int tid = threadIdx.x;
    const int w = tid >> 6, lane = tid & 63;
    const int wm = w >> 1, wn = w & 1;
    const int lhi = lane >> 4, llo = lane & 15;

    int nblk = gridDim.x;
    int q = nblk >> 3, r = nblk & 7;
    int xcd = blockIdx.x & 7, lo = blockIdx.x >> 3;
    int wg = ((xcd < r) ? xcd * (q + 1) : r * (q + 1) + (xcd - r) * q) + lo;
    int mt = wg % g.MT, nt = wg / g.MT;
    const int row0 = mt * 128, col0 = nt * 128;

    const int lr8 = lane >> 3;
    const int cs = (lane & 7) ^ lr8;
    const ushort* pA[4];
    const ushort* pB[4];
    #pragma unroll
    for (int qq = 0; qq < 4; ++qq) {
        int seg = w + qq * 4;
        int ra = row0 + seg * 8 + lr8; if (ra > g.M - 1) ra = g.M - 1;
        int rb = col0 + seg * 8 + lr8; if (rb > g.N - 1) rb = g.N - 1;
        pA[qq] = g.A + (size_t)ra * g.lda + cs * 8;
        pB[qq] = g.B + (size_t)rb * g.ldb + cs * 8;
    }

    f32x4 acc[4][4] = {};

    #pragma unroll
    for (int qq = 0; qq < 4; ++qq) {
        int seg = w + qq * 4;
        GLOAD_LDS16(pA[qq], (char*)As + (seg << 10));
        GLOAD_LDS16(pB[qq], (char*)Bs + (seg << 10));
    }
    __syncthreads();

    int cur = 0;
    for (int kk = 0; kk < g.Kp; kk += 64) {
        if (kk + 64 < g.Kp) {
            int nb = (cur ^ 1) << 14;   // byte offset of next buffer (16KB)
            #pragma unroll
            for (int qq = 0; qq < 4; ++qq) {
                int seg = w + qq * 4;
                GLOAD_LDS16(pA[qq] + kk + 64, (char*)As + nb + (seg << 10));
                GLOAD_LDS16(pB[qq] + kk + 64, (char*)Bs + nb + (seg << 10));
            }
        }
        const char* curA = (const char*)As + (cur << 14);
        const char* curB = (const char*)Bs + (cur << 14);
        #pragma unroll
        for (int ks = 0; ks < 2; ++ks) {
            short8b af[4], bg[4];
            #pragma unroll
            for (int i = 0; i < 4; ++i) {
                int Ra = wm * 64 + i * 16 + llo;
                int ca = (ks * 4 + lhi) ^ (Ra & 7);
                af[i] = *(const short8b*)(curA + Ra * 128 + (ca << 4));
                int Rb = wn * 64 + i * 16 + llo;
                int cbs = (ks * 4 + lhi) ^ (Rb & 7);
                bg[i] = *(const short8b*)(curB + Rb * 128 + (cbs << 4));
            }
            #pragma unroll
            for (int i = 0; i < 4; ++i)
                #pragma unroll
                for (int j = 0; j < 4; ++j)
                    acc[i][j] = __builtin_amdgcn_mfma_f32_16x16x32_bf16(af[i], bg[j], acc[i][j], 0, 0, 0);
        }
        __syncthreads();    // drains vmcnt(0): next buffer staged; cur reads done
        cur ^= 1;
    }

    if (MODE == 0) {
        #pragma unroll
        for (int i = 0; i < 4; ++i) {
            #pragma unroll
            for (int reg = 0; reg < 4; ++reg) {
                int row = row0 + wm * 64 + i * 16 + lhi * 4 + reg;
                if (row >= g.M) continue;
                #pragma unroll
                for (int j = 0; j < 4; ++j) {
                    int col = col0 + wn * 64 + j * 16 + llo;
                    if (col < g.N)
                        g.C[(size_t)row * g.ldc + col] = acc[i][j][reg] + (g.bias ? g.bias[col] : 0.f);
                }
            }
        }
    } else if (MODE == 1) {
        #pragma unroll
        for (int i = 0; i < 4; ++i) {
            #pragma unroll
            for (int reg = 0; reg < 4; ++reg) {
                int row = row0 + wm * 64 + i * 16 + lhi * 4 + reg;
                float vals[4], vmax = -1e30f;
                #pragma unroll
                for (int j = 0; j < 4; ++j) {
                    int col = col0 + wn * 64 + j * 16 + llo;
                    vals[j] = (col < g.N) ? (acc[i][j][reg] + g.bias[col]) : -1e30f;
                    vmax = fmaxf(vmax, vals[j]);
                }
                #pragma unroll
                for (int off = 8; off; off >>= 1) vmax = fmaxf(vmax, __shfl_xor(vmax, off, 16));
                float se = 0.f;
                #pragma unroll
                for (int j = 0; j < 4; ++j) {
                    int col = col0 + wn * 64 + j * 16 + llo;
                    if (col < g.N) se += __expf(vals[j] - vmax);
                }
                #pragma unroll
                for (int off = 8; off; off >>= 1) se += __shfl_xor(se, off, 16);
                if (llo == 0 && row < g.M) {
                    g.pm[(size_t)row * NST + nt * 2 + wn] = vmax;
                    g.ps[(size_t)row * NST + nt * 2 + wn] = se;
                }
            }
        }
    } else {   // MODE 2: fused maxout; C = tmax fp32 (ldc), Cb = bf16 [*,1024]
        #pragma unroll
        for (int i = 0; i < 4; ++i) {
            #pragma unroll
            for (int reg = 0; reg < 4; ++reg) {
                int row = row0 + wm * 64 + i * 16 + lhi * 4 + reg;
                #pragma unroll
                for (int j = 0; j < 4; ++j) {
                    int col = col0 + wn * 64 + j * 16 + llo;
                    int cc = col < g.N ? col : 0;
                    float bv = g.bias[cc] + (g.bias2 ? g.bias2[cc] : 0.f) + (g.bias3 ? g.bias3[cc] : 0.f);
                    float v = acc[i][j][reg] + bv;
                    float o = fmaxf(v, __shfl_xor(v, 1));   // pair (2m, 2m+1)
                    if (((llo & 1) == 0) && row < g.M) {
                        int m = col >> 1;
                        if (col + 1 < g.N) {
                            g.C[(size_t)row * g.ldc + m] = o;
                            g.Cb[(size_t)row * 1024 + m] = f2bf(o);
                        } else if (col >= g.N && m < 1024) {
                            g.Cb[(size_t)row * 1024 + m] = 0;   // pad slots 1000..1023
                        }
                    }
                }
            }
        }
    }
}

template <int MODE>
__global__ __launch_bounds__(256) void gemm_one(GemmArgs g) {
    __shared__ __align__(16) ushort As[2 * 128 * 64];
    __shared__ __align__(16) ushort Bs[2 * 128 * 64];
    gemm_body<MODE>(As, Bs, g);
}

__global__ __launch_bounds__(256) void gemm_pair(GemmArgs g0, GemmArgs g1) {
    __shared__ __align__(16) ushort As[2 * 128 * 64];
    __shared__ __align__(16) ushort Bs[2 * 128 * 64];
    if (blockIdx.y == 0) gemm_body<0>(As, Bs, g0);
    else                 gemm_body<0>(As, Bs, g1);
}

// ---------------- persistent LSTM: all 20 steps, enc+dec, one dispatch ------
// (R9/R11-verified variant: 232 us; only change: poll s_sleep 1 -> 8 to cut
// LLC flag-poll contention.) grid (63,2) = 126 blocks co-resident.
__global__ __launch_bounds__(512) void lstm_all(
    const float* __restrict__ xpE, const float* __restrict__ xpD,
    const ushort* __restrict__ WE, const ushort* __restrict__ WD,
    ushort* __restrict__ hE, ushort* __restrict__ hD,
    int strideE, int strideD, unsigned* __restrict__ flags)
{
    __shared__ float gsm[8][32][16];
    const int which = blockIdx.y;
    const float* xp = which ? xpD : xpE;
    const ushort* Whh = which ? WD : WE;
    ushort* hs = which ? hD : hE;
    const int hstride = which ? strideD : strideE;
    unsigned* fl = flags + which * 64;         // 63 flags per network

    const int tid = threadIdx.x;
    const int wave = tid >> 6, l = tid & 63;
    const int g = wave & 3, half = wave >> 2;
    const int lhi = l >> 4, llo = l & 15;
    const int j0 = blockIdx.x * 16;
    const int jc = (j0 + llo < Hh) ? (j0 + llo) : (Hh - 1);
    const int kbase = half * 512;
    const ushort* wp = Whh + (size_t)(g * Hh + jc) * 1024 + kbase + lhi * 8;

    short8b wreg[16];
    #pragma unroll
    for (int kk = 0; kk < 16; ++kk) wreg[kk] = *(const short8b*)(wp + kk * 32);

    const int ub = tid >> 4, ujj = tid & 15;   // update-stage mapping
    const int ujw = j0 + ujj;
    const float* xpr = xp + (size_t)ub * Tt * Gg;
    float creg = 0.f;

    for (int t = 0; t < Tt; ++t) {
        f32x4 acc0 = {0.f, 0.f, 0.f, 0.f};
        f32x4 acc1 = {0.f, 0.f, 0.f, 0.f};
        if (t > 0) {
            const ushort* h0p = hs + ((size_t)llo * Tt + (t - 1)) * hstride + kbase + lhi * 8;
            const ushort* h1p = hs + ((size_t)(llo + 16) * Tt + (t - 1)) * hstride + kbase + lhi * 8;
            short8b a0r[4], a1r[4];
            #pragma unroll
            for (int pp = 0; pp < 4; ++pp) {
                a0r[pp] = *(const short8b*)(h0p + pp * 32);
                a1r[pp] = *(const short8b*)(h1p + pp * 32);
            }
            #pragma unroll
            for (int kk = 0; kk < 16; ++kk) {
                short8b a0 = a0r[kk & 3], a1 = a1r[kk & 3];
                if (kk + 4 < 16) {
                    a0r[kk & 3] = *(const short8b*)(h0p + (kk + 4) * 32);
                    a1r[kk & 3] = *(const short8b*)(h1p + (kk + 4) * 32);
                }
                acc0 = __builtin_amdgcn_mfma_f32_16x16x32_bf16(a0, wreg[kk], acc0, 0, 0, 0);
                acc1 = __builtin_amdgcn_mfma_f32_16x16x32_bf16(a1, wreg[kk], acc1, 0, 0, 0);
            }
        }
        #pragma unroll
        for (int reg = 0; reg < 4; ++reg) {
            gsm[wave][lhi * 4 + reg][llo]      = acc0[reg];
            gsm[wave][16 + lhi * 4 + reg][llo] = acc1[reg];
        }
        __syncthreads();
        {
            const float* xq = xpr + (size_t)t * Gg;
            float hn = 0.f;
            if (ujw < Hh) {
                float vi = gsm[0][ub][ujj] + gsm[4][ub][ujj] + xq[ujw];
                float vf = gsm[1][ub][ujj] + gsm[5][ub][ujj] + xq[Hh + ujw];
                float vg = gsm[2][ub][ujj] + gsm[6][ub][ujj] + xq[2 * Hh + ujw];
                float vo = gsm[3][ub][ujj] + gsm[7][ub][ujj] + xq[3 * Hh + ujw];
                creg = sigf(vf) * creg + sigf(vi) * tanhf(vg);
                hn = sigf(vo) * tanhf(creg);
            }
            unsigned mine = f2bf(hn);
            unsigned other = (unsigned)__shfl_xor((int)mine, 1);
            if (((ujj & 1) == 0) && ujw < Hh) {
                unsigned pk = (other << 16) | (mine & 0xFFFFu);
                unsigned* dst = (unsigned*)&hs[((size_t)ub * Tt + t) * hstride + ujw];
                __hip_atomic_store(dst, pk, __ATOMIC_RELAXED, __HIP_MEMORY_SCOPE_SYSTEM);
            }
        }
        if (t + 1 < Tt) {
            __syncthreads();                  // h-stores drained (vmcnt 0)
            if (tid == 0)
                __hip_atomic_store(&fl[blockIdx.x], (unsigned)(t + 1),
                                   __ATOMIC_RELAXED, __HIP_MEMORY_SCOPE_SYSTEM);
            if (tid < 64) {                   // wave 0: parallel flag poll
                unsigned tgt = (unsigned)(t + 1);
                while (true) {
                    unsigned v = (tid < 63)
                        ? __hip_atomic_load(&fl[tid], __ATOMIC_RELAXED, __HIP_MEMORY_SCOPE_SYSTEM)
                        : tgt;
                    if (__all(v >= tgt)) break;
                    __builtin_amdgcn_s_sleep(8);
                }
            }
            __syncthreads();                  // also protects gsm reuse
        }
    }
}

// ---------------- attention scores: one wave per (b,s,t) (R9 variant) -------
__global__ __launch_bounds__(256) void attn_scores(
    const float* __restrict__ Ua, const float* __restrict__ Wa,
    const float* __restrict__ Va_w, const float* __restrict__ Va_b,
    float* __restrict__ scores)
{
    int wave = (blockIdx.x * 256 + threadIdx.x) >> 6;
    int lane = threadIdx.x & 63;
    if (wave >= Bb * Ss * Tt) return;
    int b = wave / (Ss * Tt);
    int rem = wave % (Ss * Tt);
    int s = rem / Tt, t = rem % Tt;
    const float* ua = Ua + (size_t)(b * Ss + s) * Hh;
    const float* wa = Wa + (size_t)(b * Tt + t) * Hh;
    float acc = 0.f;
    for (int h = lane; h < Hh; h += 64)
        acc += tanhf(ua[h] + wa[h]) * Va_w[h];
    #pragma unroll
    for (int off = 32; off; off >>= 1) acc += __shfl_xor(acc, off, 64);
    if (lane == 0) scores[(size_t)(b * Ss + s) * Tt + t] = acc + Va_b[0];
}

// ---------------- softmax over s + context (bf16 in, bf16 out into A_cat) --
__global__ __launch_bounds__(256) void softmax_context(
    const float* __restrict__ scores, const ushort* __restrict__ enc_hb,
    ushort* __restrict__ ctx_out, int ostride)
{
    __shared__ float w[Ss];
    int b = blockIdx.x / Tt, t = blockIdx.x % Tt;
    if (threadIdx.x == 0) {
        float sc[Ss];
        float mx = -1e30f;
        for (int s = 0; s < Ss; ++s) {
            sc[s] = scores[(size_t)(b * Ss + s) * Tt + t];
            mx = fmaxf(mx, sc[s]);
        }
        float sum = 0.f;
        for (int s = 0; s < Ss; ++s) { float e = __expf(sc[s] - mx); w[s] = e; sum += e; }
        float inv = 1.f / sum;
        for (int s = 0; s < Ss; ++s) w[s] *= inv;
    }
    __syncthreads();
    for (int h = threadIdx.x; h < Hh; h += 256) {
        float acc = 0.f;
        #pragma unroll
        for (int s = 0; s < Ss; ++s)
            acc += w[s] * bf2f(enc_hb[((size_t)b * Ss + s) * 1024 + h]);
        ctx_out[(size_t)(b * Tt + t) * ostride + h] = f2bf(acc);
    }
}

// ---------------- per-row NLL + fused final loss (ready-counter) -----------
__global__ __launch_bounds__(256) void nll_kernel(
    const float* __restrict__ pm, const float* __restrict__ ps,
    const float* __restrict__ tmax, const float* __restrict__ Ww,
    const float* __restrict__ Wb, const int* __restrict__ y,
    float* __restrict__ nll, unsigned* __restrict__ ready,
    float* __restrict__ out)
{
    __shared__ float sm[4];
    __shared__ unsigned lastf;
    int row = blockIdx.x;
    int tid = threadIdx.x;
    float mx = -1e30f;
    for (int i = tid; i < NST; i += 256) mx = fmaxf(mx, pm[(size_t)row * NST + i]);
    #pragma unroll
    for (int off = 32; off; off >>= 1) mx = fmaxf(mx, __shfl_xor(mx, off, 64));
    if ((tid & 63) == 0) sm[tid >> 6] = mx;
    __syncthreads();
    mx = fmaxf(fmaxf(sm[0], sm[1]), fmaxf(sm[2], sm[3]));
    __syncthreads();
    float s = 0.f;
    for (int i = tid; i < NST; i += 256)
        s += ps[(size_t)row * NST + i] * __expf(pm[(size_t)row * NST + i] - mx);
    #pragma unroll
    for (int off = 32; off; off >>= 1) s += __shfl_xor(s, off, 64);
    if ((tid & 63) == 0) sm[tid >> 6] = s;
    __syncthreads();
    s = sm[0] + sm[1] + sm[2] + sm[3];
    __syncthreads();
    int b = row / Tt, t = row % Tt;
    int lab = y[b * (Tt + 1) + t + 1];
    float d = 0.f;
    for (int m = tid; m < Mm; m += 256)
        d += tmax[(size_t)row * Mm + m] * Ww[(size_t)lab * Mm + m];
    #pragma unroll
    for (int off = 32; off; off >>= 1) d += __shfl_xor(d, off, 64);
    if ((tid & 63) == 0) sm[tid >> 6] = d;
    __syncthreads();
    d = sm[0] + sm[1] + sm[2] + sm[3] + Wb[lab];
    if (tid == 0) {
        float v = (mx + logf(s)) - d;
        __hip_atomic_store(&nll[row], v, __ATOMIC_RELAXED, __HIP_MEMORY_SCOPE_SYSTEM);
        asm volatile("s_waitcnt vmcnt(0)" ::: "memory");   // store acked at coherent pt
        lastf = __hip_atomic_fetch_add(ready, 1u, __ATOMIC_RELAXED, __HIP_MEMORY_SCOPE_AGENT);
    }
    __syncthreads();
    if (lastf == (unsigned)(Bb * Tt - 1)) {    // last block: final reduce
        float acc = 0.f;
        for (int i = tid; i < Bb * Tt; i += 256)
            acc += __hip_atomic_load(&nll[i], __ATOMIC_RELAXED, __HIP_MEMORY_SCOPE_SYSTEM);
        #pragma unroll
        for (int off = 32; off; off >>= 1) acc += __shfl_xor(acc, off, 64);
        if ((tid & 63) == 0) sm[tid >> 6] = acc;
        __syncthreads();
        if (tid == 0) out[0] = (sm[0] + sm[1] + sm[2] + sm[3]) / (float)Bb;
    }
}

extern "C" void kernel_launch(void* const* d_in, const int* in_sizes, int n_in,
                              void* d_out, int out_size, void* d_ws, size_t ws_size,
                              hipStream_t stream)
{
    const int* x = (const int*)d_in[0];
    const int* y = (const int*)d_in[1];
    const float* emb_de  = (const float*)d_in[2];
    const float* emb_en  = (const float*)d_in[3];
    const float* enc_Wih = (const float*)d_in[4];
    const float* enc_Whh = (const float*)d_in[5];
    const float* enc_b   = (const float*)d_in[6];
    const float* dec_Wih = (const float*)d_in[7];
    const float* dec_Whh = (const float*)d_in[8];
    const float* dec_b   = (const float*)d_in[9];
    const float* Wa_w = (const float*)d_in[10];
    const float* Wa_b = (const float*)d_in[11];
    const float* Ua_w = (const float*)d_in[12];
    const float* Ua_b = (const float*)d_in[13];
    const float* Va_w = (const float*)d_in[14];
    const float* Va_b = (const float*)d_in[15];
    const float* U_w  = (const float*)d_in[16];
    const float* U_b  = (const float*)d_in[17];
    const float* V_w  = (const float*)d_in[18];
    const float* V_b  = (const float*)d_in[19];
    const float* C_w  = (const float*)d_in[20];
    const float* C_b  = (const float*)d_in[21];
    const float* W_w  = (const float*)d_in[22];
    const float* W_b  = (const float*)d_in[23];

    char* base = (char*)d_ws;
    size_t off = 0;
    auto alloc = [&](size_t bytes) { char* p = base + off; off += (bytes + 255) & ~(size_t)255; return p; };

    float*  xp_enc   = (float*)alloc(640ull * 4000 * 4);   // alias: tmax
    float*  xp_dec   = (float*)alloc(640ull * 4000 * 4);   // alias: tmax_b
    float*  Wa       = (float*)alloc(640ull * 1000 * 4);
    float*  Ua       = (float*)alloc(640ull * 1000 * 4);
    float*  scores   = (float*)alloc((size_t)Bb * Ss * Tt * 4);
    float*  pm       = (float*)alloc(640ull * NST * 4);
    float*  ps       = (float*)alloc(640ull * NST * 4);
    float*  nll      = (float*)alloc(640ull * 4);
    ushort* e_de_b   = (ushort*)alloc(640ull * 640 * 2);
    // zero-region: A_cat | hs_enc_b | flags (contiguous, one memset)
    ushort* A_cat    = (ushort*)alloc(640ull * 2688 * 2);  // [dec_h 1024 | e_en 640 | ctx 1024]
    ushort* hs_enc_b = (ushort*)alloc(640ull * 1024 * 2);
    unsigned* flags  = (unsigned*)alloc(512);              // [0..62]=enc, [64..126]=dec, [120]=ready
    ushort* whh_enc_b= (ushort*)alloc(4000ull * 1024 * 2);
    ushort* whh_dec_b= (ushort*)alloc(4000ull * 1024 * 2);
    ushort* wbig     = (ushort*)alloc(30000ull * 1024 * 2); // W_w_b fallback; wih bufs overlay
    ushort* Wcat_b   = (ushort*)alloc(2000ull * 2688 * 2);
    ushort* Wa_w_b   = (ushort*)alloc(1000ull * 1024 * 2);
    ushort* Ua_w_b   = (ushort*)alloc(1000ull * 1024 * 2);

    ushort* wih_enc_b = wbig;                               // 4000*640 each, dead after xp GEMMs
    ushort* wih_dec_b = wbig + 4000ull * 640;

    // separate W_w_b if workspace permits -> merge its convert into conv_multi
    ushort* W_w_b = wbig;
    bool sepWw = (ws_size >= off + 30000ull * 1024 * 2 + 256);
    if (sepWw) W_w_b = (ushort*)alloc(30000ull * 1024 * 2);

    float*  tmax   = xp_enc + 640ull * 2000;                // 640*1000 f32
    ushort* tmax_b = (ushort*)xp_dec;                       // 640*1024 bf16
    unsigned* ready = &flags[120];

    dim3 blk(256);

    // one memset covers A_cat pads + hs_enc_b pads + flags + ready counter
    hipMemsetAsync(A_cat, 0, 640ull * 2688 * 2 + 640ull * 1024 * 2 + 512, stream);

    // ---- all weight conversions + BOTH embedding gathers in ONE dispatch
    ConvJobs jobs = {};
    unsigned acc = 0;
    int nj = 0;
    auto JC = [&](const float* s, ushort* d, int K, int ostr, int kp8, int R) {
        acc += (unsigned)R * kp8;
        jobs.j[nj++] = ConvJob{s, d, nullptr, acc, K, ostr, kp8, 0};
    };
    auto JG = [&](const float* emb, ushort* d, const int* tok, int tstr, int ostr) {
        acc += 640u * 80;
        jobs.j[nj++] = ConvJob{emb, d, tok, acc, Dd, ostr, 80, tstr};
    };
    JC(enc_Whh, whh_enc_b, 1000, 1024, 128, 4000);
    JC(dec_Whh, whh_dec_b, 1000, 1024, 128, 4000);
    JC(enc_Wih, wih_enc_b,  620,  640,  80, 4000);
    JC(dec_Wih, wih_dec_b,  620,  640,  80, 4000);
    JC(Wa_w,    Wa_w_b,    1000, 1024, 128, 1000);
    JC(Ua_w,    Ua_w_b,    1000, 1024, 128, 1000);
    JC(U_w,     Wcat_b,          1000, 2688, 128, 2000);
    JC(V_w,     Wcat_b + 1024,    620, 2688,  80, 2000);
    JC(C_w,     Wcat_b + 1664,   1000, 2688, 128, 2000);
    JG(emb_de, e_de_b,       x, Ss,     640);
    JG(emb_en, A_cat + 1024, y, Tt + 1, 2688);
    if (sepWw) JC(W_w, W_w_b, 1000, 1024, 128, 30000);
    for (int i = nj; i < 12; ++i) jobs.j[i].end = acc;      // defuse unused slots
    conv_multi<<<dim3((acc + 255) / 256), blk, 0, stream>>>(jobs, acc);

    // ---- xp pair: e @ Wih^T + b  [640,4000], Kp=640  (enc & dec in one launch)
    GemmArgs ge = {e_de_b, 640, wih_enc_b, 640, enc_b, nullptr, nullptr,
                   xp_enc, 4000, nullptr, nullptr, nullptr, 640, 4000, 640, 5};
    GemmArgs gd = {A_cat + 1024, 2688, wih_dec_b, 640, dec_b, nullptr, nullptr,
                   xp_dec, 4000, nullptr, nullptr, nullptr, 640, 4000, 640, 5};
    gemm_pair<<<dim3(160, 2), blk, 0, stream>>>(ge, gd);

    // ---- fallback: W_w -> bf16 overlaying wih bufs (after xp GEMMs consumed them)
    if (!sepWw)
        conv_bf16<<<dim3(15000), blk, 0, stream>>>(W_w, 1000, W_w_b, 1024, 128, 30000 * 128);

    // ---- persistent LSTM: all 20 steps, enc+dec, one dispatch
    lstm_all<<<dim3(63, 2), dim3(512), 0, stream>>>(
        xp_enc, xp_dec, whh_enc_b, whh_dec_b, hs_enc_b, A_cat, 1024, 2688, flags);

    // ---- attention projections pair  [640,1000], Kp=1024
    GemmArgs gw = {A_cat, 2688, Wa_w_b, 1024, Wa_b, nullptr, nullptr,
                   Wa, 1000, nullptr, nullptr, nullptr, 640, 1000, 1024, 5};
    GemmArgs gu = {hs_enc_b, 1024, Ua_w_b, 1024, Ua_b, nullptr, nullptr,
                   Ua, 1000, nullptr, nullptr, nullptr, 640, 1000, 1024, 5};
    gemm_pair<<<dim3(40, 2), blk, 0, stream>>>(gw, gu);

    attn_scores<<<dim3(3200), blk, 0, stream>>>(Ua, Wa, Va_w, Va_b, scores);
    softmax_context<<<dim3(640), blk, 0, stream>>>(scores, hs_enc_b, A_cat + 1664, 2688);

    // ---- u-GEMM with fused maxout + 3-way bias + pad-zeroing  [640,2000]
    GemmArgs gm = {A_cat, 2688, Wcat_b, 2688, U_b, V_b, C_b,
                   tmax, 1000, nullptr, nullptr, tmax_b, 640, 2000, 2688, 5};
    gemm_one<2><<<dim3(80), blk, 0, stream>>>(gm);

    // ---- logits GEMM + fused logsumexp partials  [640,30000], Kp=1024
    GemmArgs gl = {tmax_b, 1024, W_w_b, 1024, W_b, nullptr, nullptr,
                   nullptr, 0, pm, ps, nullptr, 640, VEN_, 1024, 5};
    gemm_one<1><<<dim3(1175), blk, 0, stream>>>(gl);

    // ---- per-row NLL + fused final loss (last block reduces)
    nll_kernel<<<dim3(640), blk, 0, stream>>>(pm, ps, tmax, W_w, W_b, y,
                                              nll, ready, (float*)d_out);
}

// Round 13
// 489.131 us; speedup vs baseline: 1.9253x; 1.0626x over previous
//
#include <hip/hip_runtime.h>
#include <math.h>

#define VEN_  30000
#define Dd    620
#define Hh    1000
#define Gg    4000   // 4*H
#define Mm    1000
#define Bb    32
#define Ss    20
#define Tt    20
#define NST   470    // 2 * ceil(30000/128) stat slots per row

typedef __attribute__((ext_vector_type(8))) short short8b;  // 8 bf16
typedef __attribute__((ext_vector_type(4))) float f32x4;

typedef __attribute__((address_space(1))) void GASV;
typedef __attribute__((address_space(3))) void LASV;
#define GLOAD_LDS16(g, l) \
    __builtin_amdgcn_global_load_lds((GASV*)(const void*)(g), (LASV*)(void*)(l), 16, 0, 0)

__device__ __forceinline__ float sigf(float x) { return 1.0f / (1.0f + __expf(-x)); }
__device__ __forceinline__ ushort f2bf(float f) {            // RNE fp32->bf16
    unsigned u = __float_as_uint(f);
    u = (u + 0x7fffu + ((u >> 16) & 1u)) >> 16;
    return (ushort)u;
}
__device__ __forceinline__ float bf2f(ushort u) { return __uint_as_float(((unsigned)u) << 16); }
__device__ __forceinline__ short8b cvt8(float4 a, float4 b) {
    ushort v[8];
    v[0] = f2bf(a.x); v[1] = f2bf(a.y); v[2] = f2bf(a.z); v[3] = f2bf(a.w);
    v[4] = f2bf(b.x); v[5] = f2bf(b.y); v[6] = f2bf(b.z); v[7] = f2bf(b.w);
    return *(short8b*)v;
}

// ---------------- fp32 -> bf16 convert, vectorized, K-padded (fallback) ----
__global__ void conv_bf16(const float* __restrict__ in, int K,
                          ushort* __restrict__ out, int ostride, int kp8, int total) {
    int idx = blockIdx.x * 256 + threadIdx.x;
    if (idx >= total) return;                 // total = R * kp8
    int rr = idx / kp8, c8 = (idx % kp8) * 8;
    const float* src = in + (size_t)rr * K + c8;
    short8b o;
    if (c8 + 7 < K) {
        o = cvt8(*(const float4*)src, *(const float4*)(src + 4));
    } else {
        ushort v[8];
        #pragma unroll
        for (int j = 0; j < 8; ++j) v[j] = (c8 + j < K) ? f2bf(src[j]) : (ushort)0;
        o = *(short8b*)v;
    }
    *(short8b*)&out[(size_t)rr * ostride + c8] = o;
}

// ------- merged multi-tensor convert + embedding gathers (one dispatch) -----
struct ConvJob {
    const float* src; ushort* dst; const int* tok;
    unsigned end; int K; int ostride; int kp8; int tstride;
};
struct ConvJobs { ConvJob j[12]; };

__global__ void conv_multi(ConvJobs jobs, unsigned total) {
    unsigned v = blockIdx.x * 256 + threadIdx.x;
    if (v >= total) return;
    int ji = 0;
    while (v >= jobs.j[ji].end) ++ji;         // ends ascending, bounded
    unsigned base = ji ? jobs.j[ji - 1].end : 0;
    unsigned local = v - base;
    const ConvJob J = jobs.j[ji];
    int rr = local / J.kp8, c8 = (local % J.kp8) * 8;
    int srow = rr;
    if (J.tok) srow = J.tok[(rr / Tt) * J.tstride + (rr % Tt)];
    const float* src = J.src + (size_t)srow * J.K + c8;
    short8b o;
    if (c8 + 7 < J.K) {
        o = cvt8(*(const float4*)src, *(const float4*)(src + 4));
    } else {
        ushort w[8];
        #pragma unroll
        for (int j = 0; j < 8; ++j) w[j] = (c8 + j < J.K) ? f2bf(src[j]) : (ushort)0;
        o = *(short8b*)w;
    }
    *(short8b*)&J.dst[(size_t)rr * J.ostride + c8] = o;
}

// ---------------- MFMA GEMM (m97 structure + 2-phase dbuf) -----------------
struct GemmArgs {
    const ushort* A; int lda;
    const ushort* B; int ldb;
    const float* bias; const float* bias2; const float* bias3;
    float* C; int ldc;
    float* pm; float* ps; ushort* Cb;
    int M, N, Kp, MT;
};

template <int MODE>
__device__ __forceinline__ void gemm_body(ushort* As, ushort* Bs, const GemmArgs g) {
    const int tid = threadIdx.x;
    const int w = tid >> 6, lane = tid & 63;
    const int wm = w >> 1, wn = w & 1;
    const int lhi = lane >> 4, llo = lane & 15;

    int nblk = gridDim.x;
    int q = nblk >> 3, r = nblk & 7;
    int xcd = blockIdx.x & 7, lo = blockIdx.x >> 3;
    int wg = ((xcd < r) ? xcd * (q + 1) : r * (q + 1) + (xcd - r) * q) + lo;
    int mt = wg % g.MT, nt = wg / g.MT;
    const int row0 = mt * 128, col0 = nt * 128;

    const int lr8 = lane >> 3;
    const int cs = (lane & 7) ^ lr8;
    const ushort* pA[4];
    const ushort* pB[4];
    #pragma unroll
    for (int qq = 0; qq < 4; ++qq) {
        int seg = w + qq * 4;
        int ra = row0 + seg * 8 + lr8; if (ra > g.M - 1) ra = g.M - 1;
        int rb = col0 + seg * 8 + lr8; if (rb > g.N - 1) rb = g.N - 1;
        pA[qq] = g.A + (size_t)ra * g.lda + cs * 8;
        pB[qq] = g.B + (size_t)rb * g.ldb + cs * 8;
    }

    f32x4 acc[4][4] = {};

    #pragma unroll
    for (int qq = 0; qq < 4; ++qq) {
        int seg = w + qq * 4;
        GLOAD_LDS16(pA[qq], (char*)As + (seg << 10));
        GLOAD_LDS16(pB[qq], (char*)Bs + (seg << 10));
    }
    __syncthreads();

    int cur = 0;
    for (int kk = 0; kk < g.Kp; kk += 64) {
        if (kk + 64 < g.Kp) {
            int nb = (cur ^ 1) << 14;   // byte offset of next buffer (16KB)
            #pragma unroll
            for (int qq = 0; qq < 4; ++qq) {
                int seg = w + qq * 4;
                GLOAD_LDS16(pA[qq] + kk + 64, (char*)As + nb + (seg << 10));
                GLOAD_LDS16(pB[qq] + kk + 64, (char*)Bs + nb + (seg << 10));
            }
        }
        const char* curA = (const char*)As + (cur << 14);
        const char* curB = (const char*)Bs + (cur << 14);
        #pragma unroll
        for (int ks = 0; ks < 2; ++ks) {
            short8b af[4], bg[4];
            #pragma unroll
            for (int i = 0; i < 4; ++i) {
                int Ra = wm * 64 + i * 16 + llo;
                int ca = (ks * 4 + lhi) ^ (Ra & 7);
                af[i] = *(const short8b*)(curA + Ra * 128 + (ca << 4));
                int Rb = wn * 64 + i * 16 + llo;
                int cbs = (ks * 4 + lhi) ^ (Rb & 7);
                bg[i] = *(const short8b*)(curB + Rb * 128 + (cbs << 4));
            }
            #pragma unroll
            for (int i = 0; i < 4; ++i)
                #pragma unroll
                for (int j = 0; j < 4; ++j)
                    acc[i][j] = __builtin_amdgcn_mfma_f32_16x16x32_bf16(af[i], bg[j], acc[i][j], 0, 0, 0);
        }
        __syncthreads();    // drains vmcnt(0): next buffer staged; cur reads done
        cur ^= 1;
    }

    if (MODE == 0) {
        #pragma unroll
        for (int i = 0; i < 4; ++i) {
            #pragma unroll
            for (int reg = 0; reg < 4; ++reg) {
                int row = row0 + wm * 64 + i * 16 + lhi * 4 + reg;
                if (row >= g.M) continue;
                #pragma unroll
                for (int j = 0; j < 4; ++j) {
                    int col = col0 + wn * 64 + j * 16 + llo;
                    if (col < g.N)
                        g.C[(size_t)row * g.ldc + col] = acc[i][j][reg] + (g.bias ? g.bias[col] : 0.f);
                }
            }
        }
    } else if (MODE == 1) {
        #pragma unroll
        for (int i = 0; i < 4; ++i) {
            #pragma unroll
            for (int reg = 0; reg < 4; ++reg) {
                int row = row0 + wm * 64 + i * 16 + lhi * 4 + reg;
                float vals[4], vmax = -1e30f;
                #pragma unroll
                for (int j = 0; j < 4; ++j) {
                    int col = col0 + wn * 64 + j * 16 + llo;
                    vals[j] = (col < g.N) ? (acc[i][j][reg] + g.bias[col]) : -1e30f;
                    vmax = fmaxf(vmax, vals[j]);
                }
                #pragma unroll
                for (int off = 8; off; off >>= 1) vmax = fmaxf(vmax, __shfl_xor(vmax, off, 16));
                float se = 0.f;
                #pragma unroll
                for (int j = 0; j < 4; ++j) {
                    int col = col0 + wn * 64 + j * 16 + llo;
                    if (col < g.N) se += __expf(vals[j] - vmax);
                }
                #pragma unroll
                for (int off = 8; off; off >>= 1) se += __shfl_xor(se, off, 16);
                if (llo == 0 && row < g.M) {
                    g.pm[(size_t)row * NST + nt * 2 + wn] = vmax;
                    g.ps[(size_t)row * NST + nt * 2 + wn] = se;
                }
            }
        }
    } else {   // MODE 2: fused maxout; C = tmax fp32 (ldc), Cb = bf16 [*,1024]
        #pragma unroll
        for (int i = 0; i < 4; ++i) {
            #pragma unroll
            for (int reg = 0; reg < 4; ++reg) {
                int row = row0 + wm * 64 + i * 16 + lhi * 4 + reg;
                #pragma unroll
                for (int j = 0; j < 4; ++j) {
                    int col = col0 + wn * 64 + j * 16 + llo;
                    int cc = col < g.N ? col : 0;
                    float bv = g.bias[cc] + (g.bias2 ? g.bias2[cc] : 0.f) + (g.bias3 ? g.bias3[cc] : 0.f);
                    float v = acc[i][j][reg] + bv;
                    float o = fmaxf(v, __shfl_xor(v, 1));   // pair (2m, 2m+1)
                    if (((llo & 1) == 0) && row < g.M) {
                        int m = col >> 1;
                        if (col + 1 < g.N) {
                            g.C[(size_t)row * g.ldc + m] = o;
                            g.Cb[(size_t)row * 1024 + m] = f2bf(o);
                        } else if (col >= g.N && m < 1024) {
                            g.Cb[(size_t)row * 1024 + m] = 0;   // pad slots 1000..1023
                        }
                    }
                }
            }
        }
    }
}

template <int MODE>
__global__ __launch_bounds__(256) void gemm_one(GemmArgs g) {
    __shared__ __align__(16) ushort As[2 * 128 * 64];
    __shared__ __align__(16) ushort Bs[2 * 128 * 64];
    gemm_body<MODE>(As, Bs, g);
}

__global__ __launch_bounds__(256) void gemm_pair(GemmArgs g0, GemmArgs g1) {
    __shared__ __align__(16) ushort As[2 * 128 * 64];
    __shared__ __align__(16) ushort Bs[2 * 128 * 64];
    if (blockIdx.y == 0) gemm_body<0>(As, Bs, g0);
    else                 gemm_body<0>(As, Bs, g1);
}

// ---------------- persistent LSTM: all 20 steps, enc+dec, one dispatch ------
// R12 base + this round: (1) wreg pinned in VGPRs via empty asm (compiler was
// re-streaming 128KB/block of weights from L2 every step — VGPR_Count 52 < 64
// proved it); (2) h stored as 8B packed (4 cols) system-scope atomics, 4x
// fewer coherent-point transactions on the release path; (3) xq prefetched
// at iteration top (hides L2 latency under the MFMA phase).
__global__ __launch_bounds__(512) void lstm_all(
    const float* __restrict__ xpE, const float* __restrict__ xpD,
    const ushort* __restrict__ WE, const ushort* __restrict__ WD,
    ushort* __restrict__ hE, ushort* __restrict__ hD,
    int strideE, int strideD, unsigned* __restrict__ flags)
{
    __shared__ float gsm[8][32][16];
    const int which = blockIdx.y;
    const float* xp = which ? xpD : xpE;
    const ushort* Whh = which ? WD : WE;
    ushort* hs = which ? hD : hE;
    const int hstride = which ? strideD : strideE;
    unsigned* fl = flags + which * 64;         // 63 flags per network

    const int tid = threadIdx.x;
    const int wave = tid >> 6, l = tid & 63;
    const int g = wave & 3, half = wave >> 2;
    const int lhi = l >> 4, llo = l & 15;
    const int j0 = blockIdx.x * 16;
    const int jc = (j0 + llo < Hh) ? (j0 + llo) : (Hh - 1);
    const int kbase = half * 512;
    const ushort* wp = Whh + (size_t)(g * Hh + jc) * 1024 + kbase + lhi * 8;

    // hoist weights into registers and PIN them (block rematerialization)
    short8b wreg[16];
    #pragma unroll
    for (int kk = 0; kk < 16; ++kk) wreg[kk] = *(const short8b*)(wp + kk * 32);
    #pragma unroll
    for (int kk = 0; kk < 16; ++kk) asm volatile("" : "+v"(wreg[kk]));

    const int ub = tid >> 4, ujj = tid & 15;   // update-stage mapping
    const int ujw = j0 + ujj;
    const float* xpr = xp + (size_t)ub * Tt * Gg;
    float creg = 0.f;

    for (int t = 0; t < Tt; ++t) {
        // xq prefetch (independent of h[t-1]; hides under the MFMA phase)
        float xq0 = 0.f, xq1 = 0.f, xq2 = 0.f, xq3 = 0.f;
        if (ujw < Hh) {
            const float* xq = xpr + (size_t)t * Gg;
            xq0 = xq[ujw]; xq1 = xq[Hh + ujw]; xq2 = xq[2 * Hh + ujw]; xq3 = xq[3 * Hh + ujw];
        }

        f32x4 acc0 = {0.f, 0.f, 0.f, 0.f};
        f32x4 acc1 = {0.f, 0.f, 0.f, 0.f};
        if (t > 0) {
            const ushort* h0p = hs + ((size_t)llo * Tt + (t - 1)) * hstride + kbase + lhi * 8;
            const ushort* h1p = hs + ((size_t)(llo + 16) * Tt + (t - 1)) * hstride + kbase + lhi * 8;
            short8b a0r[4], a1r[4];
            #pragma unroll
            for (int pp = 0; pp < 4; ++pp) {
                a0r[pp] = *(const short8b*)(h0p + pp * 32);
                a1r[pp] = *(const short8b*)(h1p + pp * 32);
            }
            #pragma unroll
            for (int kk = 0; kk < 16; ++kk) {
                short8b a0 = a0r[kk & 3], a1 = a1r[kk & 3];
                if (kk + 4 < 16) {
                    a0r[kk & 3] = *(const short8b*)(h0p + (kk + 4) * 32);
                    a1r[kk & 3] = *(const short8b*)(h1p + (kk + 4) * 32);
                }
                acc0 = __builtin_amdgcn_mfma_f32_16x16x32_bf16(a0, wreg[kk], acc0, 0, 0, 0);
                acc1 = __builtin_amdgcn_mfma_f32_16x16x32_bf16(a1, wreg[kk], acc1, 0, 0, 0);
            }
        }
        #pragma unroll
        for (int reg = 0; reg < 4; ++reg) {
            gsm[wave][lhi * 4 + reg][llo]      = acc0[reg];
            gsm[wave][16 + lhi * 4 + reg][llo] = acc1[reg];
        }
        __syncthreads();
        {
            float hn = 0.f;
            if (ujw < Hh) {
                float vi = gsm[0][ub][ujj] + gsm[4][ub][ujj] + xq0;
                float vf = gsm[1][ub][ujj] + gsm[5][ub][ujj] + xq1;
                float vg = gsm[2][ub][ujj] + gsm[6][ub][ujj] + xq2;
                float vo = gsm[3][ub][ujj] + gsm[7][ub][ujj] + xq3;
                creg = sigf(vf) * creg + sigf(vi) * tanhf(vg);
                hn = sigf(vo) * tanhf(creg);
            }
            // pack 4 cols -> one u64, system-scope write-through store.
            // Pad cols (>=Hh) store zeros (hn=0) — matches the memset contract.
            unsigned mine = f2bf(hn);
            unsigned other = (unsigned)__shfl_xor((int)mine, 1);
            unsigned pk = (other << 16) | (mine & 0xFFFFu);     // cols (ujw,ujw+1) at even ujj
            unsigned pk2 = (unsigned)__shfl_xor((int)pk, 2);    // cols (ujw+2,ujw+3)
            if ((ujj & 3) == 0) {
                unsigned long long val = (unsigned long long)pk | ((unsigned long long)pk2 << 32);
                unsigned long long* dst = (unsigned long long*)&hs[((size_t)ub * Tt + t) * hstride + ujw];
                __hip_atomic_store(dst, val, __ATOMIC_RELAXED, __HIP_MEMORY_SCOPE_SYSTEM);
            }
        }
        if (t + 1 < Tt) {
            __syncthreads();                  // h-stores drained (vmcnt 0)
            if (tid == 0)
                __hip_atomic_store(&fl[blockIdx.x], (unsigned)(t + 1),
                                   __ATOMIC_RELAXED, __HIP_MEMORY_SCOPE_SYSTEM);
            if (tid < 64) {                   // wave 0: parallel flag poll
                unsigned tgt = (unsigned)(t + 1);
                while (true) {
                    unsigned v = (tid < 63)
                        ? __hip_atomic_load(&fl[tid], __ATOMIC_RELAXED, __HIP_MEMORY_SCOPE_SYSTEM)
                        : tgt;
                    if (__all(v >= tgt)) break;
                    __builtin_amdgcn_s_sleep(8);
                }
            }
            __syncthreads();                  // also protects gsm reuse
        }
    }
}

// ---------------- attention scores: one wave per (b,s,t) (R9 variant) -------
__global__ __launch_bounds__(256) void attn_scores(
    const float* __restrict__ Ua, const float* __restrict__ Wa,
    const float* __restrict__ Va_w, const float* __restrict__ Va_b,
    float* __restrict__ scores)
{
    int wave = (blockIdx.x * 256 + threadIdx.x) >> 6;
    int lane = threadIdx.x & 63;
    if (wave >= Bb * Ss * Tt) return;
    int b = wave / (Ss * Tt);
    int rem = wave % (Ss * Tt);
    int s = rem / Tt, t = rem % Tt;
    const float* ua = Ua + (size_t)(b * Ss + s) * Hh;
    const float* wa = Wa + (size_t)(b * Tt + t) * Hh;
    float acc = 0.f;
    for (int h = lane; h < Hh; h += 64)
        acc += tanhf(ua[h] + wa[h]) * Va_w[h];
    #pragma unroll
    for (int off = 32; off; off >>= 1) acc += __shfl_xor(acc, off, 64);
    if (lane == 0) scores[(size_t)(b * Ss + s) * Tt + t] = acc + Va_b[0];
}

// ---------------- softmax over s + context (bf16 in, bf16 out into A_cat) --
__global__ __launch_bounds__(256) void softmax_context(
    const float* __restrict__ scores, const ushort* __restrict__ enc_hb,
    ushort* __restrict__ ctx_out, int ostride)
{
    __shared__ float w[Ss];
    int b = blockIdx.x / Tt, t = blockIdx.x % Tt;
    if (threadIdx.x == 0) {
        float sc[Ss];
        float mx = -1e30f;
        for (int s = 0; s < Ss; ++s) {
            sc[s] = scores[(size_t)(b * Ss + s) * Tt + t];
            mx = fmaxf(mx, sc[s]);
        }
        float sum = 0.f;
        for (int s = 0; s < Ss; ++s) { float e = __expf(sc[s] - mx); w[s] = e; sum += e; }
        float inv = 1.f / sum;
        for (int s = 0; s < Ss; ++s) w[s] *= inv;
    }
    __syncthreads();
    for (int h = threadIdx.x; h < Hh; h += 256) {
        float acc = 0.f;
        #pragma unroll
        for (int s = 0; s < Ss; ++s)
            acc += w[s] * bf2f(enc_hb[((size_t)b * Ss + s) * 1024 + h]);
        ctx_out[(size_t)(b * Tt + t) * ostride + h] = f2bf(acc);
    }
}

// ---------------- per-row NLL + fused final loss (ready-counter) -----------
__global__ __launch_bounds__(256) void nll_kernel(
    const float* __restrict__ pm, const float* __restrict__ ps,
    const float* __restrict__ tmax, const float* __restrict__ Ww,
    const float* __restrict__ Wb, const int* __restrict__ y,
    float* __restrict__ nll, unsigned* __restrict__ ready,
    float* __restrict__ out)
{
    __shared__ float sm[4];
    __shared__ unsigned lastf;
    int row = blockIdx.x;
    int tid = threadIdx.x;
    float mx = -1e30f;
    for (int i = tid; i < NST; i += 256) mx = fmaxf(mx, pm[(size_t)row * NST + i]);
    #pragma unroll
    for (int off = 32; off; off >>= 1) mx = fmaxf(mx, __shfl_xor(mx, off, 64));
    if ((tid & 63) == 0) sm[tid >> 6] = mx;
    __syncthreads();
    mx = fmaxf(fmaxf(sm[0], sm[1]), fmaxf(sm[2], sm[3]));
    __syncthreads();
    float s = 0.f;
    for (int i = tid; i < NST; i += 256)
        s += ps[(size_t)row * NST + i] * __expf(pm[(size_t)row * NST + i] - mx);
    #pragma unroll
    for (int off = 32; off; off >>= 1) s += __shfl_xor(s, off, 64);
    if ((tid & 63) == 0) sm[tid >> 6] = s;
    __syncthreads();
    s = sm[0] + sm[1] + sm[2] + sm[3];
    __syncthreads();
    int b = row / Tt, t = row % Tt;
    int lab = y[b * (Tt + 1) + t + 1];
    float d = 0.f;
    for (int m = tid; m < Mm; m += 256)
        d += tmax[(size_t)row * Mm + m] * Ww[(size_t)lab * Mm + m];
    #pragma unroll
    for (int off = 32; off; off >>= 1) d += __shfl_xor(d, off, 64);
    if ((tid & 63) == 0) sm[tid >> 6] = d;
    __syncthreads();
    d = sm[0] + sm[1] + sm[2] + sm[3] + Wb[lab];
    if (tid == 0) {
        float v = (mx + logf(s)) - d;
        __hip_atomic_store(&nll[row], v, __ATOMIC_RELAXED, __HIP_MEMORY_SCOPE_SYSTEM);
        asm volatile("s_waitcnt vmcnt(0)" ::: "memory");   // store acked at coherent pt
        lastf = __hip_atomic_fetch_add(ready, 1u, __ATOMIC_RELAXED, __HIP_MEMORY_SCOPE_AGENT);
    }
    __syncthreads();
    if (lastf == (unsigned)(Bb * Tt - 1)) {    // last block: final reduce
        float acc = 0.f;
        for (int i = tid; i < Bb * Tt; i += 256)
            acc += __hip_atomic_load(&nll[i], __ATOMIC_RELAXED, __HIP_MEMORY_SCOPE_SYSTEM);
        #pragma unroll
        for (int off = 32; off; off >>= 1) acc += __shfl_xor(acc, off, 64);
        if ((tid & 63) == 0) sm[tid >> 6] = acc;
        __syncthreads();
        if (tid == 0) out[0] = (sm[0] + sm[1] + sm[2] + sm[3]) / (float)Bb;
    }
}

extern "C" void kernel_launch(void* const* d_in, const int* in_sizes, int n_in,
                              void* d_out, int out_size, void* d_ws, size_t ws_size,
                              hipStream_t stream)
{
    const int* x = (const int*)d_in[0];
    const int* y = (const int*)d_in[1];
    const float* emb_de  = (const float*)d_in[2];
    const float* emb_en  = (const float*)d_in[3];
    const float* enc_Wih = (const float*)d_in[4];
    const float* enc_Whh = (const float*)d_in[5];
    const float* enc_b   = (const float*)d_in[6];
    const float* dec_Wih = (const float*)d_in[7];
    const float* dec_Whh = (const float*)d_in[8];
    const float* dec_b   = (const float*)d_in[9];
    const float* Wa_w = (const float*)d_in[10];
    const float* Wa_b = (const float*)d_in[11];
    const float* Ua_w = (const float*)d_in[12];
    const float* Ua_b = (const float*)d_in[13];
    const float* Va_w = (const float*)d_in[14];
    const float* Va_b = (const float*)d_in[15];
    const float* U_w  = (const float*)d_in[16];
    const float* U_b  = (const float*)d_in[17];
    const float* V_w  = (const float*)d_in[18];
    const float* V_b  = (const float*)d_in[19];
    const float* C_w  = (const float*)d_in[20];
    const float* C_b  = (const float*)d_in[21];
    const float* W_w  = (const float*)d_in[22];
    const float* W_b  = (const float*)d_in[23];

    char* base = (char*)d_ws;
    size_t off = 0;
    auto alloc = [&](size_t bytes) { char* p = base + off; off += (bytes + 255) & ~(size_t)255; return p; };

    float*  xp_enc   = (float*)alloc(640ull * 4000 * 4);   // alias: tmax
    float*  xp_dec   = (float*)alloc(640ull * 4000 * 4);   // alias: tmax_b
    float*  Wa       = (float*)alloc(640ull * 1000 * 4);
    float*  Ua       = (float*)alloc(640ull * 1000 * 4);
    float*  scores   = (float*)alloc((size_t)Bb * Ss * Tt * 4);
    float*  pm       = (float*)alloc(640ull * NST * 4);
    float*  ps       = (float*)alloc(640ull * NST * 4);
    float*  nll      = (float*)alloc(640ull * 4);
    ushort* e_de_b   = (ushort*)alloc(640ull * 640 * 2);
    // zero-region: A_cat | hs_enc_b | flags (contiguous, one memset)
    ushort* A_cat    = (ushort*)alloc(640ull * 2688 * 2);  // [dec_h 1024 | e_en 640 | ctx 1024]
    ushort* hs_enc_b = (ushort*)alloc(640ull * 1024 * 2);
    unsigned* flags  = (unsigned*)alloc(512);              // [0..62]=enc, [64..126]=dec, [120]=ready
    ushort* whh_enc_b= (ushort*)alloc(4000ull * 1024 * 2);
    ushort* whh_dec_b= (ushort*)alloc(4000ull * 1024 * 2);
    ushort* wbig     = (ushort*)alloc(30000ull * 1024 * 2); // W_w_b fallback; wih bufs overlay
    ushort* Wcat_b   = (ushort*)alloc(2000ull * 2688 * 2);
    ushort* Wa_w_b   = (ushort*)alloc(1000ull * 1024 * 2);
    ushort* Ua_w_b   = (ushort*)alloc(1000ull * 1024 * 2);

    ushort* wih_enc_b = wbig;                               // 4000*640 each, dead after xp GEMMs
    ushort* wih_dec_b = wbig + 4000ull * 640;

    // separate W_w_b if workspace permits -> merge its convert into conv_multi
    ushort* W_w_b = wbig;
    bool sepWw = (ws_size >= off + 30000ull * 1024 * 2 + 256);
    if (sepWw) W_w_b = (ushort*)alloc(30000ull * 1024 * 2);

    float*  tmax   = xp_enc + 640ull * 2000;                // 640*1000 f32
    ushort* tmax_b = (ushort*)xp_dec;                       // 640*1024 bf16
    unsigned* ready = &flags[120];

    dim3 blk(256);

    // one memset covers A_cat pads + hs_enc_b pads + flags + ready counter
    hipMemsetAsync(A_cat, 0, 640ull * 2688 * 2 + 640ull * 1024 * 2 + 512, stream);

    // ---- all weight conversions + BOTH embedding gathers in ONE dispatch
    ConvJobs jobs = {};
    unsigned acc = 0;
    int nj = 0;
    auto JC = [&](const float* s, ushort* d, int K, int ostr, int kp8, int R) {
        acc += (unsigned)R * kp8;
        jobs.j[nj++] = ConvJob{s, d, nullptr, acc, K, ostr, kp8, 0};
    };
    auto JG = [&](const float* emb, ushort* d, const int* tok, int tstr, int ostr) {
        acc += 640u * 80;
        jobs.j[nj++] = ConvJob{emb, d, tok, acc, Dd, ostr, 80, tstr};
    };
    JC(enc_Whh, whh_enc_b, 1000, 1024, 128, 4000);
    JC(dec_Whh, whh_dec_b, 1000, 1024, 128, 4000);
    JC(enc_Wih, wih_enc_b,  620,  640,  80, 4000);
    JC(dec_Wih, wih_dec_b,  620,  640,  80, 4000);
    JC(Wa_w,    Wa_w_b,    1000, 1024, 128, 1000);
    JC(Ua_w,    Ua_w_b,    1000, 1024, 128, 1000);
    JC(U_w,     Wcat_b,          1000, 2688, 128, 2000);
    JC(V_w,     Wcat_b + 1024,    620, 2688,  80, 2000);
    JC(C_w,     Wcat_b + 1664,   1000, 2688, 128, 2000);
    JG(emb_de, e_de_b,       x, Ss,     640);
    JG(emb_en, A_cat + 1024, y, Tt + 1, 2688);
    if (sepWw) JC(W_w, W_w_b, 1000, 1024, 128, 30000);
    for (int i = nj; i < 12; ++i) jobs.j[i].end = acc;      // defuse unused slots
    conv_multi<<<dim3((acc + 255) / 256), blk, 0, stream>>>(jobs, acc);

    // ---- xp pair: e @ Wih^T + b  [640,4000], Kp=640  (enc & dec in one launch)
    GemmArgs ge = {e_de_b, 640, wih_enc_b, 640, enc_b, nullptr, nullptr,
                   xp_enc, 4000, nullptr, nullptr, nullptr, 640, 4000, 640, 5};
    GemmArgs gd = {A_cat + 1024, 2688, wih_dec_b, 640, dec_b, nullptr, nullptr,
                   xp_dec, 4000, nullptr, nullptr, nullptr, 640, 4000, 640, 5};
    gemm_pair<<<dim3(160, 2), blk, 0, stream>>>(ge, gd);

    // ---- fallback: W_w -> bf16 overlaying wih bufs (after xp GEMMs consumed them)
    if (!sepWw)
        conv_bf16<<<dim3(15000), blk, 0, stream>>>(W_w, 1000, W_w_b, 1024, 128, 30000 * 128);

    // ---- persistent LSTM: all 20 steps, enc+dec, one dispatch
    lstm_all<<<dim3(63, 2), dim3(512), 0, stream>>>(
        xp_enc, xp_dec, whh_enc_b, whh_dec_b, hs_enc_b, A_cat, 1024, 2688, flags);

    // ---- attention projections pair  [640,1000], Kp=1024
    GemmArgs gw = {A_cat, 2688, Wa_w_b, 1024, Wa_b, nullptr, nullptr,
                   Wa, 1000, nullptr, nullptr, nullptr, 640, 1000, 1024, 5};
    GemmArgs gu = {hs_enc_b, 1024, Ua_w_b, 1024, Ua_b, nullptr, nullptr,
                   Ua, 1000, nullptr, nullptr, nullptr, 640, 1000, 1024, 5};
    gemm_pair<<<dim3(40, 2), blk, 0, stream>>>(gw, gu);

    attn_scores<<<dim3(3200), blk, 0, stream>>>(Ua, Wa, Va_w, Va_b, scores);
    softmax_context<<<dim3(640), blk, 0, stream>>>(scores, hs_enc_b, A_cat + 1664, 2688);

    // ---- u-GEMM with fused maxout + 3-way bias + pad-zeroing  [640,2000]
    GemmArgs gm = {A_cat, 2688, Wcat_b, 2688, U_b, V_b, C_b,
                   tmax, 1000, nullptr, nullptr, tmax_b, 640, 2000, 2688, 5};
    gemm_one<2><<<dim3(80), blk, 0, stream>>>(gm);

    // ---- logits GEMM + fused logsumexp partials  [640,30000], Kp=1024
    GemmArgs gl = {tmax_b, 1024, W_w_b, 1024, W_b, nullptr, nullptr,
                   nullptr, 0, pm, ps, nullptr, 640, VEN_, 1024, 5};
    gemm_one<1><<<dim3(1175), blk, 0, stream>>>(gl);

    // ---- per-row NLL + fused final loss (last block reduces)
    nll_kernel<<<dim3(640), blk, 0, stream>>>(pm, ps, tmax, W_w, W_b, y,
                                              nll, ready, (float*)d_out);
}